// Round 20
// baseline (1760.895 us; speedup 1.0000x reference)
//
#include <hip/hip_runtime.h>

// Encoder: 3x [conv1d(K=5,pad2)+BN+ReLU] -> biLSTM(H=256) zoneout(0.1).  MFMA convs/gates; int8 VALU recurrence.
// r20: XOR slot-swizzle (g' = g ^ (row&3)) on conv/gates LDS tiles -- kills the pitch-40 16B-slot bank
//   collisions (2.2e7 conflict-cycles = ~30% of conv time). Pure layout permutation, bit-identical math.
//   lstm unchanged from r19 (int8 resident weights).
// ws:    A f16 @0 (32,768,000) | G f16 [2][100][32][1024] @32,768,000 (13,107,200)
//        | state @45,875,200 (131,072) | W8 @46,006,272 (524,288) | scl f32[2048] @46,530,560 (8,192)
//        | Wg f16 [2][1024][512] @47,054,848 (2,097,152) -> 49,152,000 B
// d_out: Bd (conv1 out) @0 | Wp0 @36,000,000 | Wp1 @36,409,600 | Wp2 @41,652,480 | Xt0 @46,895,360

#define T_LEN 1000
#define NBATCH 32
#define CCH 512
#define HDIM 256
#define GDIM 1024
#define TC 100

typedef _Float16 h16;
typedef _Float16 h16x2 __attribute__((ext_vector_type(2)));
typedef _Float16 f16x8 __attribute__((ext_vector_type(8)));
typedef float    f32x4 __attribute__((ext_vector_type(4)));

__device__ __forceinline__ float fixup(float v, float alt){
    union { float f; unsigned u; } c; c.f = v;
    return ((c.u & 0x7f800000u) == 0x7f800000u) ? alt : v;
}
__device__ __forceinline__ float clamp_s(float v, float lo, float hi){
    return fminf(fmaxf(v, lo), hi);
}
__device__ __forceinline__ float sigm(float x){
    const float xc = clamp_s(x, -30.f, 30.f);
    return 1.0f / (1.0f + __expf(-xc));
}
__device__ __forceinline__ float tanh_safe(float x){
    const float ax = fminf(fabsf(x), 30.0f);
    const float t  = __expf(-2.0f * ax);
    const float r  = (1.0f - t) / (1.0f + t);
    return copysignf(r, x);
}
// v_dot4_i32_i8: 4 int8 MACs + i32 accumulate
__device__ __forceinline__ int dot4i8(int a, int b, int c){
#if defined(__has_builtin) && __has_builtin(__builtin_amdgcn_sdot4)
    return __builtin_amdgcn_sdot4(a, b, c, false);
#else
    int r = c;
    #pragma unroll
    for (int k = 0; k < 4; ++k) {
        const int av = (a << (24 - 8*k)) >> 24;
        const int bv = (b << (24 - 8*k)) >> 24;
        r += av * bv;
    }
    return r;
#endif
}

// ---------------- packs ----------------
__global__ __launch_bounds__(256)
void pack_convw_kernel(const float* __restrict__ cw, h16* __restrict__ Wp, int cin)
{
    const int n = blockIdx.x*256 + threadIdx.x;
    if (n >= 5*512*cin) return;
    const int k   = n / (512*cin);
    const int rem = n - k*512*cin;
    const int co  = rem / cin;
    const int ci  = rem - co*cin;
    Wp[n] = (h16)cw[((size_t)co*cin + ci)*5 + k];
}

__global__ __launch_bounds__(256)
void pack_wih_kernel(const float* __restrict__ wf, const float* __restrict__ wb, h16* __restrict__ Wg)
{
    const int n = blockIdx.x*256 + threadIdx.x;
    const float* src = (n < 1024*512) ? wf : wb;
    Wg[n] = (h16)src[n & (1024*512 - 1)];
}

// per-row |max| -> dot-scale scl[dir*1024+row] = max/(127*127)
__global__ __launch_bounds__(256)
void whh_scale_kernel(const float* __restrict__ whh_f, const float* __restrict__ whh_b,
                      float* __restrict__ scl)
{
    const int n = blockIdx.x*256 + threadIdx.x;   // 2048
    if (n >= 2048) return;
    const float* whh = (n >= 1024) ? whh_b : whh_f;
    const int row = n & 1023;
    float m = 0.f;
    for (int k = 0; k < HDIM; ++k) m = fmaxf(m, fabsf(whh[(size_t)row*HDIM + k]));
    scl[n] = fmaxf(m, 1e-8f) / 16129.0f;
}

// whh f32 -> int8 chunk-major pack (r19 mapping).
__global__ __launch_bounds__(256)
void whh_prep_kernel(const float* __restrict__ whh_f, const float* __restrict__ whh_b,
                     const float* __restrict__ scl, unsigned* __restrict__ W8)
{
    const int n = blockIdx.x * 256 + threadIdx.x;   // 131072 u32
    if (n >= 2*16*1024*4) return;
    const int dir   = n >> 16;
    const int rem   = n & 65535;
    const int chunk = rem >> 12;
    const int idx   = rem & 4095;
    const int t     = idx >> 2;
    const int e     = idx & 3;
    const float* whh = dir ? whh_b : whh_f;
    const int half = (t >> 6) & 1;
    const int qq   = t >> 7;
    const int l    = t & 63;
    const int rA   = qq*128 + 2*l;
    int row, g;
    if (chunk < 8)       { row = rA + 1; g = chunk; }
    else if (chunk == 8) { row = rA;     g = 7; }
    else                 { row = rA;     g = chunk - 9; }
    const float inv = 1.0f / (scl[dir*1024 + row] * 127.0f);   // = 127/max
    const int k0 = 128*half + 16*g + 4*e;
    unsigned u = 0;
    #pragma unroll
    for (int j = 0; j < 4; ++j) {
        const float w = whh[(size_t)row*HDIM + k0 + j];
        int qv = (int)rintf(w * inv);
        qv = qv > 127 ? 127 : (qv < -127 ? -127 : qv);
        u |= ((unsigned)(qv & 0xFF)) << (8*j);
    }
    W8[n] = u;
}

__global__ __launch_bounds__(256)
void x0_transpose_kernel(const float* __restrict__ x, h16* __restrict__ Xt0)
{
    const int b = blockIdx.y;
    const int t = blockIdx.x*256 + threadIdx.x;
    if (t >= T_LEN) return;
    h16 v[80];
    #pragma unroll
    for (int c = 0; c < 80; ++c) v[c] = (h16)x[((size_t)b*80 + c)*T_LEN + t];
    #pragma unroll
    for (int g = 0; g < 10; ++g)
        *(f16x8*)(Xt0 + ((size_t)b*T_LEN + t)*80 + g*8) = *(const f16x8*)(v + g*8);
}

// ---------------- conv (implicit GEMM, MFMA 16x16x32 f16, swizzled LDS) ----------------
// Slot-swizzle: 16-B slot g within a row stored at slot (g ^ (row & 3)) -- same permutation
// on write and read => bit-identical math, banks spread across rows.
__global__ __attribute__((amdgpu_flat_work_group_size(512,512), amdgpu_waves_per_eu(4,4)))
void conv_mfma_kernel(const h16* __restrict__ Xt, const h16* __restrict__ Wp,
                      h16* __restrict__ outp,
                      const float* __restrict__ cb, const float* __restrict__ bg,
                      const float* __restrict__ bb, const float* __restrict__ bm,
                      const float* __restrict__ bv, int cin)
{
    const int t0   = blockIdx.x * 128;
    const int co0  = blockIdx.y * 128;
    const int b    = blockIdx.z;
    const int tid  = threadIdx.x;
    const int lane = tid & 63;
    const int w    = tid >> 6;
    const int wm   = w >> 2;
    const int wn   = w & 3;
    const int lr   = lane & 15;
    const int lg   = lane >> 4;

    __shared__ __align__(16) h16 Xs[132*40];
    __shared__ __align__(16) h16 Ws[5*128*40];

    f32x4 acc[4][2];
    #pragma unroll
    for (int m = 0; m < 4; ++m)
        #pragma unroll
        for (int n = 0; n < 2; ++n)
            #pragma unroll
            for (int r = 0; r < 4; ++r) acc[m][n][r] = 0.f;

    const int ksteps = (cin + 31) >> 5;
    for (int cs = 0; cs < ksteps; ++cs) {
        const int c0 = cs << 5;
        for (int id = tid; id < 132*4; id += 512) {
            const int row = id >> 2, g = id & 3;
            const int t = t0 + row - 2;
            f16x8 v;
            #pragma unroll
            for (int j = 0; j < 8; ++j) v[j] = (h16)0.f;
            if (t >= 0 && t < T_LEN) {
                const int c = c0 + g*8;
                if (c + 8 <= cin) {
                    v = *(const f16x8*)(Xt + ((size_t)b*T_LEN + t)*cin + c);
                } else if (c < cin) {
                    #pragma unroll
                    for (int j = 0; j < 8; ++j) if (c + j < cin) v[j] = Xt[((size_t)b*T_LEN + t)*cin + c + j];
                }
            }
            *(f16x8*)(Xs + row*40 + ((g ^ (row & 3))*8)) = v;
        }
        for (int id = tid; id < 5*128*4; id += 512) {
            const int k  = id >> 9;
            const int co = (id >> 2) & 127;
            const int g  = id & 3;
            const int c  = c0 + g*8;
            f16x8 v;
            #pragma unroll
            for (int j = 0; j < 8; ++j) v[j] = (h16)0.f;
            if (c + 8 <= cin) {
                v = *(const f16x8*)(Wp + ((size_t)k*512 + co0 + co)*cin + c);
            } else if (c < cin) {
                #pragma unroll
                for (int j = 0; j < 8; ++j) if (c + j < cin) v[j] = Wp[((size_t)k*512 + co0 + co)*cin + c + j];
            }
            *(f16x8*)(Ws + (k*128 + co)*40 + ((g ^ (co & 3))*8)) = v;
        }
        __syncthreads();

        #pragma unroll
        for (int k = 0; k < 5; ++k) {
            const int wr0 = wn*32 + lr;
            const int wr1 = wn*32 + 16 + lr;
            const f16x8 b0 = *(const f16x8*)(Ws + (k*128 + wr0)*40 + ((lg ^ (wr0 & 3))*8));
            const f16x8 b1 = *(const f16x8*)(Ws + (k*128 + wr1)*40 + ((lg ^ (wr1 & 3))*8));
            #pragma unroll
            for (int m = 0; m < 4; ++m) {
                const int xr = wm*64 + m*16 + lr + k;
                const f16x8 a = *(const f16x8*)(Xs + xr*40 + ((lg ^ (xr & 3))*8));
                acc[m][0] = __builtin_amdgcn_mfma_f32_16x16x32_f16(a, b0, acc[m][0], 0, 0, 0);
                acc[m][1] = __builtin_amdgcn_mfma_f32_16x16x32_f16(a, b1, acc[m][1], 0, 0, 0);
            }
        }
        __syncthreads();
    }

    #pragma unroll
    for (int nf = 0; nf < 2; ++nf) {
        const int co = co0 + wn*32 + nf*16 + lr;
        const float s  = bg[co] * rsqrtf(fmaxf(bv[co] + 1e-5f, 1e-8f));
        const float sh = (cb[co] - bm[co]) * s + bb[co];
        #pragma unroll
        for (int m = 0; m < 4; ++m) {
            #pragma unroll
            for (int r = 0; r < 4; ++r) {
                const int t = t0 + wm*64 + m*16 + lg*4 + r;
                if (t < T_LEN) {
                    const float y = fixup(clamp_s(fmaxf(acc[m][nf][r]*s + sh, 0.f), 0.f, 60000.f), 0.f);
                    outp[((size_t)b*T_LEN + t)*CCH + co] = (h16)y;
                }
            }
        }
    }
}

// ---------------- gates GEMM (MFMA), swizzled LDS, one time-chunk, both dirs ----------------
__global__ __attribute__((amdgpu_flat_work_group_size(256,256), amdgpu_waves_per_eu(4,4)))
void gates_mfma_kernel(const h16* __restrict__ Xt,
                       const h16* __restrict__ Wg,
                       const float* __restrict__ bih_f, const float* __restrict__ bhh_f,
                       const float* __restrict__ bih_b, const float* __restrict__ bhh_b,
                       h16* __restrict__ G, int t0f, int t0b)
{
    const int tt   = blockIdx.x;
    const int r0   = blockIdx.y * 128;
    const int b    = blockIdx.z & 31;
    const int dir  = blockIdx.z >> 5;
    const int t0c  = dir ? t0b : t0f;
    const int tid  = threadIdx.x;
    const int lane = tid & 63;
    const int w    = tid >> 6;
    const int lr   = lane & 15;
    const int lg   = lane >> 4;
    const float* bi = dir ? bih_b : bih_f;
    const float* bh = dir ? bhh_b : bhh_f;
    const h16* Wd = Wg + (size_t)dir*1024*512;

    __shared__ __align__(16) h16 Xs[64*40];
    __shared__ __align__(16) h16 Ws[128*40];

    f32x4 acc[4][2];
    #pragma unroll
    for (int m = 0; m < 4; ++m)
        #pragma unroll
        for (int n = 0; n < 2; ++n)
            #pragma unroll
            for (int r = 0; r < 4; ++r) acc[m][n][r] = 0.f;

    for (int cs = 0; cs < 16; ++cs) {
        const int c0 = cs << 5;
        for (int id = tid; id < 64*4; id += 256) {
            const int row = id >> 2, g = id & 3;
            int t = t0c + tt*64 + row; if (t >= T_LEN) t = T_LEN - 1;
            *(f16x8*)(Xs + row*40 + ((g ^ (row & 3))*8))
                = *(const f16x8*)(Xt + ((size_t)b*T_LEN + t)*CCH + c0 + g*8);
        }
        for (int id = tid; id < 128*4; id += 256) {
            const int row = id >> 2, g = id & 3;
            *(f16x8*)(Ws + row*40 + ((g ^ (row & 3))*8))
                = *(const f16x8*)(Wd + (size_t)(r0 + row)*CCH + c0 + g*8);
        }
        __syncthreads();

        const int wr0 = w*32 + lr;
        const int wr1 = w*32 + 16 + lr;
        const f16x8 b0 = *(const f16x8*)(Ws + wr0*40 + ((lg ^ (wr0 & 3))*8));
        const f16x8 b1 = *(const f16x8*)(Ws + wr1*40 + ((lg ^ (wr1 & 3))*8));
        #pragma unroll
        for (int m = 0; m < 4; ++m) {
            const int xr = m*16 + lr;
            const f16x8 a = *(const f16x8*)(Xs + xr*40 + ((lg ^ (xr & 3))*8));
            acc[m][0] = __builtin_amdgcn_mfma_f32_16x16x32_f16(a, b0, acc[m][0], 0, 0, 0);
            acc[m][1] = __builtin_amdgcn_mfma_f32_16x16x32_f16(a, b1, acc[m][1], 0, 0, 0);
        }
        __syncthreads();
    }

    #pragma unroll
    for (int nf = 0; nf < 2; ++nf) {
        const int row = r0 + w*32 + nf*16 + lr;
        const float bias = bi[row] + bh[row];
        #pragma unroll
        for (int m = 0; m < 4; ++m) {
            #pragma unroll
            for (int r = 0; r < 4; ++r) {
                const int tl = tt*64 + m*16 + lg*4 + r;
                if (tl < TC)
                    G[(((size_t)dir*TC + tl)*NBATCH + b)*GDIM + row]
                        = (h16)fixup(clamp_s(acc[m][nf][r] + bias, -60000.f, 60000.f), 0.f);
            }
        }
    }
}

// ---------------- persistent biLSTM recurrence: int8, weights fully resident (r19, unchanged) ----------
__global__ __attribute__((amdgpu_flat_work_group_size(1024, 1024), amdgpu_waves_per_eu(4, 4)))
void lstm_chunk_kernel(const h16* __restrict__ G,
                       const unsigned* __restrict__ W8,
                       const float* __restrict__ scl,
                       float* __restrict__ state,
                       float* __restrict__ out,
                       int t0f, int t0b, int first)
{
    const int tid  = threadIdx.x;
    const int lane = tid & 63;
    const int half = (tid >> 6) & 1;
    const int q    = tid >> 7;
    const int dir  = blockIdx.x >> 5;
    const int b    = blockIdx.x & 31;
    const int t0   = dir ? t0b : t0f;
    float* st = state + ((size_t)(dir*NBATCH + b))*2*HDIM;
    const uint4* Wg8 = (const uint4*)W8 + (size_t)dir*16384;

    __shared__ __align__(16) uint4 lw8[7*1024];        // 112 KB: rowA g0..6
    __shared__ __align__(4)  unsigned char hq8[256];   // h int8
    __shared__ float pbuf[2*GDIM];                     // 8 KB

    uint4 rb[8];
    #pragma unroll
    for (int g = 0; g < 8; ++g) rb[g] = Wg8[g*1024 + tid];     // rowB g0..7
    const uint4 ra7 = Wg8[8*1024 + tid];                       // rowA g7

    #pragma unroll
    for (int s = 0; s < 7; ++s)
        lw8[s*1024 + tid] = Wg8[(9 + s)*1024 + tid];           // rowA g0..6 -> LDS

    const int rA = q*128 + 2*lane;
    const float sclA = scl[dir*1024 + rA];
    const float sclB = scl[dir*1024 + rA + 1];

    float hst = 0.0f, cst = 0.0f;
    if (tid < HDIM) {
        if (!first) { hst = st[tid]; cst = st[HDIM + tid]; }
        const int qh = (int)rintf(clamp_s(hst, -1.f, 1.f) * 127.f);
        hq8[tid] = (unsigned char)(qh & 0xFF);
    }
    __syncthreads();

    float2* pbuf2 = (float2*)pbuf;
    float prev_h = 0.0f;
    int   prev_t = -1;

    for (int i = 0; i < TC; ++i) {
        const int sl = dir ? (TC - 1 - i) : i;
        const int t  = t0 + sl;
        const h16* gp = G + (((size_t)dir*TC + sl)*NBATCH + b)*GDIM;

        const unsigned wv = ((const unsigned*)hq8)[(half << 5) | (lane & 31)];

        float g0 = 0.f, g1 = 0.f, g2 = 0.f, g3 = 0.f;
        if (tid < HDIM) {
            if (prev_t >= 0)
                out[((size_t)b*T_LEN + prev_t)*(2*HDIM) + dir*HDIM + tid] = prev_h;
            g0 = (float)gp[tid];
            g1 = (float)gp[HDIM + tid];
            g2 = (float)gp[2*HDIM + tid];
            g3 = (float)gp[3*HDIM + tid];
        }

        int accA = 0, accB = 0;
        #pragma unroll
        for (int g = 0; g < 8; ++g) {
            const int s0 = __builtin_amdgcn_readlane((int)wv, 4*g + 0);
            const int s1 = __builtin_amdgcn_readlane((int)wv, 4*g + 1);
            const int s2 = __builtin_amdgcn_readlane((int)wv, 4*g + 2);
            const int s3 = __builtin_amdgcn_readlane((int)wv, 4*g + 3);
            const uint4 wA = (g < 7) ? lw8[g*1024 + tid] : ra7;
            const uint4 wB = rb[g];
            accA = dot4i8(s0, (int)wA.x, accA);
            accA = dot4i8(s1, (int)wA.y, accA);
            accA = dot4i8(s2, (int)wA.z, accA);
            accA = dot4i8(s3, (int)wA.w, accA);
            accB = dot4i8(s0, (int)wB.x, accB);
            accB = dot4i8(s1, (int)wB.y, accB);
            accB = dot4i8(s2, (int)wB.z, accB);
            accB = dot4i8(s3, (int)wB.w, accB);
        }

        pbuf2[(half << 9) | (q << 6) | lane] = make_float2((float)accA * sclA, (float)accB * sclB);
        __syncthreads();

        if (tid < HDIM) {
            const float gi = g0 + pbuf[tid]            + pbuf[GDIM + tid];
            const float gf = g1 + pbuf[HDIM + tid]     + pbuf[GDIM + HDIM + tid];
            const float gg = g2 + pbuf[2*HDIM + tid]   + pbuf[GDIM + 2*HDIM + tid];
            const float go = g3 + pbuf[3*HDIM + tid]   + pbuf[GDIM + 3*HDIM + tid];
            const float c2 = sigm(gf)*cst + sigm(gi)*tanh_safe(gg);
            const float h2 = sigm(go)*tanh_safe(c2);
            hst = 0.1f*hst + 0.9f*h2;                   // zoneout (output is post-zoneout h)
            cst = 0.1f*cst + 0.9f*c2;
            prev_h = fixup(hst, 50.0f);
            prev_t = t;
            const int qh = (int)rintf(clamp_s(hst, -1.f, 1.f) * 127.f);
            hq8[tid] = (unsigned char)(qh & 0xFF);
        }
        __syncthreads();
    }

    if (tid < HDIM) {
        if (prev_t >= 0)
            out[((size_t)b*T_LEN + prev_t)*(2*HDIM) + dir*HDIM + tid] = prev_h;
        st[tid] = hst; st[HDIM + tid] = cst;
    }
}

extern "C" void kernel_launch(void* const* d_in, const int* in_sizes, int n_in,
                              void* d_out, int out_size, void* d_ws, size_t ws_size,
                              hipStream_t stream)
{
    (void)in_sizes; (void)n_in; (void)out_size;
    if (ws_size < 49152000) return;

    const float* x     = (const float*)d_in[0];
    const float* cw0   = (const float*)d_in[1];
    const float* cb0   = (const float*)d_in[2];
    const float* bg0   = (const float*)d_in[3];
    const float* bb0   = (const float*)d_in[4];
    const float* bm0   = (const float*)d_in[5];
    const float* bv0   = (const float*)d_in[6];
    const float* cw1   = (const float*)d_in[7];
    const float* cb1   = (const float*)d_in[8];
    const float* bg1   = (const float*)d_in[9];
    const float* bb1   = (const float*)d_in[10];
    const float* bm1   = (const float*)d_in[11];
    const float* bv1   = (const float*)d_in[12];
    const float* cw2   = (const float*)d_in[13];
    const float* cb2   = (const float*)d_in[14];
    const float* bg2   = (const float*)d_in[15];
    const float* bb2   = (const float*)d_in[16];
    const float* bm2   = (const float*)d_in[17];
    const float* bv2   = (const float*)d_in[18];
    const float* wih_f = (const float*)d_in[19];
    const float* whh_f = (const float*)d_in[20];
    const float* bih_f = (const float*)d_in[21];
    const float* bhh_f = (const float*)d_in[22];
    const float* wih_b = (const float*)d_in[23];
    const float* whh_b = (const float*)d_in[24];
    const float* bih_b = (const float*)d_in[25];
    const float* bhh_b = (const float*)d_in[26];

    char* ws = (char*)d_ws;
    char* od = (char*)d_out;
    h16*      A   = (h16*)(ws);
    h16*      G   = (h16*)(ws + 32768000);
    float*    st  = (float*)(ws + 45875200);
    unsigned* W8  = (unsigned*)(ws + 46006272);
    float*    scl = (float*)(ws + 46530560);
    h16*      Wg  = (h16*)(ws + 47054848);
    h16*      Bd  = (h16*)(od);
    h16*      Wp0 = (h16*)(od + 36000000);
    h16*      Wp1 = (h16*)(od + 36409600);
    h16*      Wp2 = (h16*)(od + 41652480);
    h16*      Xt0 = (h16*)(od + 46895360);
    float*    out = (float*)d_out;

    // packs
    pack_convw_kernel<<<dim3((5*512*80  + 255)/256), 256, 0, stream>>>(cw0, Wp0, 80);
    pack_convw_kernel<<<dim3((5*512*512 + 255)/256), 256, 0, stream>>>(cw1, Wp1, 512);
    pack_convw_kernel<<<dim3((5*512*512 + 255)/256), 256, 0, stream>>>(cw2, Wp2, 512);
    pack_wih_kernel<<<dim3(2*1024*512/256), 256, 0, stream>>>(wih_f, wih_b, Wg);
    whh_scale_kernel<<<dim3(8), 256, 0, stream>>>(whh_f, whh_b, scl);
    whh_prep_kernel<<<dim3(512), 256, 0, stream>>>(whh_f, whh_b, scl, W8);
    x0_transpose_kernel<<<dim3(4, 32), 256, 0, stream>>>(x, Xt0);

    // convs (implicit-GEMM MFMA, swizzled)
    const dim3 cgrid(8, 4, 32);
    conv_mfma_kernel<<<cgrid, 512, 0, stream>>>(Xt0, Wp0, A,  cb0, bg0, bb0, bm0, bv0, 80);
    conv_mfma_kernel<<<cgrid, 512, 0, stream>>>(A,   Wp1, Bd, cb1, bg1, bb1, bm1, bv1, 512);
    conv_mfma_kernel<<<cgrid, 512, 0, stream>>>(Bd,  Wp2, A,  cb2, bg2, bb2, bm2, bv2, 512);

    for (int c = 0; c < T_LEN / TC; ++c) {
        const int t0f = c * TC;
        const int t0b = (T_LEN - TC) - c * TC;
        gates_mfma_kernel<<<dim3(2, 8, 64), 256, 0, stream>>>(A, Wg, bih_f, bhh_f, bih_b, bhh_b, G, t0f, t0b);
        lstm_chunk_kernel<<<dim3(64), 1024, 0, stream>>>(G, W8, scl, st, out, t0f, t0b, c == 0);
    }
}

// Round 21
// 1724.366 us; speedup vs baseline: 1.0212x; 1.0212x over previous
//
#include <hip/hip_runtime.h>

// Encoder: 3x [conv1d(K=5,pad2)+BN+ReLU] -> biLSTM(H=256) zoneout(0.1).  MFMA convs/gates; int8 VALU recurrence.
// r21: swizzle REVERTED (r20 regression: pitch-40 reads were already free 2-way; XOR made them 3-4 way).
//   lstm: weight reg-residency 9->11 chunks (44 VGPR weights + ~16 working <= 64 cap); LDS 7->5 chunks (80KB).
//   Math bit-identical to r18/r19 (same accumulation order g0..g7 per row).
// ws:    A f16 @0 (32,768,000) | G f16 [2][100][32][1024] @32,768,000 (13,107,200)
//        | state @45,875,200 (131,072) | W8 @46,006,272 (524,288) | scl f32[2048] @46,530,560 (8,192)
//        | Wg f16 [2][1024][512] @47,054,848 (2,097,152) -> 49,152,000 B
// d_out: Bd (conv1 out) @0 | Wp0 @36,000,000 | Wp1 @36,409,600 | Wp2 @41,652,480 | Xt0 @46,895,360

#define T_LEN 1000
#define NBATCH 32
#define CCH 512
#define HDIM 256
#define GDIM 1024
#define TC 100

typedef _Float16 h16;
typedef _Float16 h16x2 __attribute__((ext_vector_type(2)));
typedef _Float16 f16x8 __attribute__((ext_vector_type(8)));
typedef float    f32x4 __attribute__((ext_vector_type(4)));

__device__ __forceinline__ float fixup(float v, float alt){
    union { float f; unsigned u; } c; c.f = v;
    return ((c.u & 0x7f800000u) == 0x7f800000u) ? alt : v;
}
__device__ __forceinline__ float clamp_s(float v, float lo, float hi){
    return fminf(fmaxf(v, lo), hi);
}
__device__ __forceinline__ float sigm(float x){
    const float xc = clamp_s(x, -30.f, 30.f);
    return 1.0f / (1.0f + __expf(-xc));
}
__device__ __forceinline__ float tanh_safe(float x){
    const float ax = fminf(fabsf(x), 30.0f);
    const float t  = __expf(-2.0f * ax);
    const float r  = (1.0f - t) / (1.0f + t);
    return copysignf(r, x);
}
// v_dot4_i32_i8: 4 int8 MACs + i32 accumulate
__device__ __forceinline__ int dot4i8(int a, int b, int c){
#if defined(__has_builtin) && __has_builtin(__builtin_amdgcn_sdot4)
    return __builtin_amdgcn_sdot4(a, b, c, false);
#else
    int r = c;
    #pragma unroll
    for (int k = 0; k < 4; ++k) {
        const int av = (a << (24 - 8*k)) >> 24;
        const int bv = (b << (24 - 8*k)) >> 24;
        r += av * bv;
    }
    return r;
#endif
}

// ---------------- packs ----------------
__global__ __launch_bounds__(256)
void pack_convw_kernel(const float* __restrict__ cw, h16* __restrict__ Wp, int cin)
{
    const int n = blockIdx.x*256 + threadIdx.x;
    if (n >= 5*512*cin) return;
    const int k   = n / (512*cin);
    const int rem = n - k*512*cin;
    const int co  = rem / cin;
    const int ci  = rem - co*cin;
    Wp[n] = (h16)cw[((size_t)co*cin + ci)*5 + k];
}

__global__ __launch_bounds__(256)
void pack_wih_kernel(const float* __restrict__ wf, const float* __restrict__ wb, h16* __restrict__ Wg)
{
    const int n = blockIdx.x*256 + threadIdx.x;
    const float* src = (n < 1024*512) ? wf : wb;
    Wg[n] = (h16)src[n & (1024*512 - 1)];
}

// per-row |max| -> dot-scale scl[dir*1024+row] = max/(127*127)
__global__ __launch_bounds__(256)
void whh_scale_kernel(const float* __restrict__ whh_f, const float* __restrict__ whh_b,
                      float* __restrict__ scl)
{
    const int n = blockIdx.x*256 + threadIdx.x;   // 2048
    if (n >= 2048) return;
    const float* whh = (n >= 1024) ? whh_b : whh_f;
    const int row = n & 1023;
    float m = 0.f;
    for (int k = 0; k < HDIM; ++k) m = fmaxf(m, fabsf(whh[(size_t)row*HDIM + k]));
    scl[n] = fmaxf(m, 1e-8f) / 16129.0f;
}

// whh f32 -> int8 chunk-major pack (r21 mapping). Thread t: half=(t>>6)&1, q=t>>7, l=t&63;
// rA=q*128+2l, rB=rA+1; k-base=128*half; uint4 = 16 int8 = k-group g.
// Chunks (u32 n = dir*65536 + chunk*4096 + t*4 + e):
//   chunk 0..7  (REGS rb): row=rB, g=chunk | chunk 8..10 (REGS ra): row=rA, g=chunk-3 (5,6,7)
//   chunk 11..15 (LDS):    row=rA, g=chunk-11 (0..4)
__global__ __launch_bounds__(256)
void whh_prep_kernel(const float* __restrict__ whh_f, const float* __restrict__ whh_b,
                     const float* __restrict__ scl, unsigned* __restrict__ W8)
{
    const int n = blockIdx.x * 256 + threadIdx.x;   // 131072 u32
    if (n >= 2*16*1024*4) return;
    const int dir   = n >> 16;
    const int rem   = n & 65535;
    const int chunk = rem >> 12;
    const int idx   = rem & 4095;
    const int t     = idx >> 2;
    const int e     = idx & 3;
    const float* whh = dir ? whh_b : whh_f;
    const int half = (t >> 6) & 1;
    const int qq   = t >> 7;
    const int l    = t & 63;
    const int rA   = qq*128 + 2*l;
    int row, g;
    if (chunk < 8)        { row = rA + 1; g = chunk; }
    else if (chunk < 11)  { row = rA;     g = chunk - 3; }
    else                  { row = rA;     g = chunk - 11; }
    const float inv = 1.0f / (scl[dir*1024 + row] * 127.0f);   // = 127/max
    const int k0 = 128*half + 16*g + 4*e;
    unsigned u = 0;
    #pragma unroll
    for (int j = 0; j < 4; ++j) {
        const float w = whh[(size_t)row*HDIM + k0 + j];
        int qv = (int)rintf(w * inv);
        qv = qv > 127 ? 127 : (qv < -127 ? -127 : qv);
        u |= ((unsigned)(qv & 0xFF)) << (8*j);
    }
    W8[n] = u;
}

__global__ __launch_bounds__(256)
void x0_transpose_kernel(const float* __restrict__ x, h16* __restrict__ Xt0)
{
    const int b = blockIdx.y;
    const int t = blockIdx.x*256 + threadIdx.x;
    if (t >= T_LEN) return;
    h16 v[80];
    #pragma unroll
    for (int c = 0; c < 80; ++c) v[c] = (h16)x[((size_t)b*80 + c)*T_LEN + t];
    #pragma unroll
    for (int g = 0; g < 10; ++g)
        *(f16x8*)(Xt0 + ((size_t)b*T_LEN + t)*80 + g*8) = *(const f16x8*)(v + g*8);
}

// ---------------- conv (implicit GEMM, MFMA 16x16x32 f16) -- r19 layout (no swizzle) ----------------
__global__ __attribute__((amdgpu_flat_work_group_size(512,512), amdgpu_waves_per_eu(4,4)))
void conv_mfma_kernel(const h16* __restrict__ Xt, const h16* __restrict__ Wp,
                      h16* __restrict__ outp,
                      const float* __restrict__ cb, const float* __restrict__ bg,
                      const float* __restrict__ bb, const float* __restrict__ bm,
                      const float* __restrict__ bv, int cin)
{
    const int t0   = blockIdx.x * 128;
    const int co0  = blockIdx.y * 128;
    const int b    = blockIdx.z;
    const int tid  = threadIdx.x;
    const int lane = tid & 63;
    const int w    = tid >> 6;
    const int wm   = w >> 2;
    const int wn   = w & 3;
    const int lr   = lane & 15;
    const int lg   = lane >> 4;

    __shared__ __align__(16) h16 Xs[132*40];
    __shared__ __align__(16) h16 Ws[5*128*40];

    f32x4 acc[4][2];
    #pragma unroll
    for (int m = 0; m < 4; ++m)
        #pragma unroll
        for (int n = 0; n < 2; ++n)
            #pragma unroll
            for (int r = 0; r < 4; ++r) acc[m][n][r] = 0.f;

    const int ksteps = (cin + 31) >> 5;
    for (int cs = 0; cs < ksteps; ++cs) {
        const int c0 = cs << 5;
        for (int id = tid; id < 132*4; id += 512) {
            const int row = id >> 2, g = id & 3;
            const int t = t0 + row - 2;
            f16x8 v;
            #pragma unroll
            for (int j = 0; j < 8; ++j) v[j] = (h16)0.f;
            if (t >= 0 && t < T_LEN) {
                const int c = c0 + g*8;
                if (c + 8 <= cin) {
                    v = *(const f16x8*)(Xt + ((size_t)b*T_LEN + t)*cin + c);
                } else if (c < cin) {
                    #pragma unroll
                    for (int j = 0; j < 8; ++j) if (c + j < cin) v[j] = Xt[((size_t)b*T_LEN + t)*cin + c + j];
                }
            }
            *(f16x8*)(Xs + row*40 + g*8) = v;
        }
        for (int id = tid; id < 5*128*4; id += 512) {
            const int k  = id >> 9;
            const int co = (id >> 2) & 127;
            const int g  = id & 3;
            const int c  = c0 + g*8;
            f16x8 v;
            #pragma unroll
            for (int j = 0; j < 8; ++j) v[j] = (h16)0.f;
            if (c + 8 <= cin) {
                v = *(const f16x8*)(Wp + ((size_t)k*512 + co0 + co)*cin + c);
            } else if (c < cin) {
                #pragma unroll
                for (int j = 0; j < 8; ++j) if (c + j < cin) v[j] = Wp[((size_t)k*512 + co0 + co)*cin + c + j];
            }
            *(f16x8*)(Ws + (k*128 + co)*40 + g*8) = v;
        }
        __syncthreads();

        #pragma unroll
        for (int k = 0; k < 5; ++k) {
            const f16x8 b0 = *(const f16x8*)(Ws + (k*128 + wn*32 +      lr)*40 + lg*8);
            const f16x8 b1 = *(const f16x8*)(Ws + (k*128 + wn*32 + 16 + lr)*40 + lg*8);
            #pragma unroll
            for (int m = 0; m < 4; ++m) {
                const f16x8 a = *(const f16x8*)(Xs + (wm*64 + m*16 + lr + k)*40 + lg*8);
                acc[m][0] = __builtin_amdgcn_mfma_f32_16x16x32_f16(a, b0, acc[m][0], 0, 0, 0);
                acc[m][1] = __builtin_amdgcn_mfma_f32_16x16x32_f16(a, b1, acc[m][1], 0, 0, 0);
            }
        }
        __syncthreads();
    }

    #pragma unroll
    for (int nf = 0; nf < 2; ++nf) {
        const int co = co0 + wn*32 + nf*16 + lr;
        const float s  = bg[co] * rsqrtf(fmaxf(bv[co] + 1e-5f, 1e-8f));
        const float sh = (cb[co] - bm[co]) * s + bb[co];
        #pragma unroll
        for (int m = 0; m < 4; ++m) {
            #pragma unroll
            for (int r = 0; r < 4; ++r) {
                const int t = t0 + wm*64 + m*16 + lg*4 + r;
                if (t < T_LEN) {
                    const float y = fixup(clamp_s(fmaxf(acc[m][nf][r]*s + sh, 0.f), 0.f, 60000.f), 0.f);
                    outp[((size_t)b*T_LEN + t)*CCH + co] = (h16)y;
                }
            }
        }
    }
}

// ---------------- gates GEMM (MFMA), one time-chunk, both dirs -- r19 layout ----------------
__global__ __attribute__((amdgpu_flat_work_group_size(256,256), amdgpu_waves_per_eu(4,4)))
void gates_mfma_kernel(const h16* __restrict__ Xt,
                       const h16* __restrict__ Wg,
                       const float* __restrict__ bih_f, const float* __restrict__ bhh_f,
                       const float* __restrict__ bih_b, const float* __restrict__ bhh_b,
                       h16* __restrict__ G, int t0f, int t0b)
{
    const int tt   = blockIdx.x;
    const int r0   = blockIdx.y * 128;
    const int b    = blockIdx.z & 31;
    const int dir  = blockIdx.z >> 5;
    const int t0c  = dir ? t0b : t0f;
    const int tid  = threadIdx.x;
    const int lane = tid & 63;
    const int w    = tid >> 6;
    const int lr   = lane & 15;
    const int lg   = lane >> 4;
    const float* bi = dir ? bih_b : bih_f;
    const float* bh = dir ? bhh_b : bhh_f;
    const h16* Wd = Wg + (size_t)dir*1024*512;

    __shared__ __align__(16) h16 Xs[64*40];
    __shared__ __align__(16) h16 Ws[128*40];

    f32x4 acc[4][2];
    #pragma unroll
    for (int m = 0; m < 4; ++m)
        #pragma unroll
        for (int n = 0; n < 2; ++n)
            #pragma unroll
            for (int r = 0; r < 4; ++r) acc[m][n][r] = 0.f;

    for (int cs = 0; cs < 16; ++cs) {
        const int c0 = cs << 5;
        for (int id = tid; id < 64*4; id += 256) {
            const int row = id >> 2, g = id & 3;
            int t = t0c + tt*64 + row; if (t >= T_LEN) t = T_LEN - 1;
            *(f16x8*)(Xs + row*40 + g*8) = *(const f16x8*)(Xt + ((size_t)b*T_LEN + t)*CCH + c0 + g*8);
        }
        for (int id = tid; id < 128*4; id += 256) {
            const int row = id >> 2, g = id & 3;
            *(f16x8*)(Ws + row*40 + g*8) = *(const f16x8*)(Wd + (size_t)(r0 + row)*CCH + c0 + g*8);
        }
        __syncthreads();

        const f16x8 b0 = *(const f16x8*)(Ws + (w*32 +      lr)*40 + lg*8);
        const f16x8 b1 = *(const f16x8*)(Ws + (w*32 + 16 + lr)*40 + lg*8);
        #pragma unroll
        for (int m = 0; m < 4; ++m) {
            const f16x8 a = *(const f16x8*)(Xs + (m*16 + lr)*40 + lg*8);
            acc[m][0] = __builtin_amdgcn_mfma_f32_16x16x32_f16(a, b0, acc[m][0], 0, 0, 0);
            acc[m][1] = __builtin_amdgcn_mfma_f32_16x16x32_f16(a, b1, acc[m][1], 0, 0, 0);
        }
        __syncthreads();
    }

    #pragma unroll
    for (int nf = 0; nf < 2; ++nf) {
        const int row = r0 + w*32 + nf*16 + lr;
        const float bias = bi[row] + bh[row];
        #pragma unroll
        for (int m = 0; m < 4; ++m) {
            #pragma unroll
            for (int r = 0; r < 4; ++r) {
                const int tl = tt*64 + m*16 + lg*4 + r;
                if (tl < TC)
                    G[(((size_t)dir*TC + tl)*NBATCH + b)*GDIM + row]
                        = (h16)fixup(clamp_s(acc[m][nf][r] + bias, -60000.f, 60000.f), 0.f);
            }
        }
    }
}

// ---------------- persistent biLSTM recurrence: int8, 11 reg-chunks + 5 LDS-chunks ----------------
// Thread t: half=(t>>6)&1 (k-half), q=t>>7, l=t&63; rows rA=q*128+2l, rB=rA+1.
// REGS: rb[8] (rowB g0..7) + ra[3] (rowA g5..7) = 44 VGPR. LDS: rowA g0..4 (5 chunks, 80 KB).
// Per step: 5 ds_read_b128 + 1 ds_read_b32 + 64 dot4 + 32 readlane. Same accumulation order as r18.
__global__ __attribute__((amdgpu_flat_work_group_size(1024, 1024), amdgpu_waves_per_eu(4, 4)))
void lstm_chunk_kernel(const h16* __restrict__ G,
                       const unsigned* __restrict__ W8,
                       const float* __restrict__ scl,
                       float* __restrict__ state,
                       float* __restrict__ out,
                       int t0f, int t0b, int first)
{
    const int tid  = threadIdx.x;
    const int lane = tid & 63;
    const int half = (tid >> 6) & 1;
    const int q    = tid >> 7;
    const int dir  = blockIdx.x >> 5;
    const int b    = blockIdx.x & 31;
    const int t0   = dir ? t0b : t0f;
    float* st = state + ((size_t)(dir*NBATCH + b))*2*HDIM;
    const uint4* Wg8 = (const uint4*)W8 + (size_t)dir*16384;

    __shared__ __align__(16) uint4 lw8[5*1024];        // 80 KB: rowA g0..4
    __shared__ __align__(4)  unsigned char hq8[256];   // h int8
    __shared__ float pbuf[2*GDIM];                     // 8 KB

    // hoisted, loop-invariant weight registers (44 VGPR)
    uint4 rb[8];
    #pragma unroll
    for (int g = 0; g < 8; ++g) rb[g] = Wg8[g*1024 + tid];     // rowB g0..7
    uint4 ra0 = Wg8[8*1024 + tid];                             // rowA g5
    uint4 ra1 = Wg8[9*1024 + tid];                             // rowA g6
    uint4 ra2 = Wg8[10*1024 + tid];                            // rowA g7

    #pragma unroll
    for (int s = 0; s < 5; ++s)
        lw8[s*1024 + tid] = Wg8[(11 + s)*1024 + tid];          // rowA g0..4 -> LDS

    const int rA = q*128 + 2*lane;
    const float sclA = scl[dir*1024 + rA];
    const float sclB = scl[dir*1024 + rA + 1];

    float hst = 0.0f, cst = 0.0f;
    if (tid < HDIM) {
        if (!first) { hst = st[tid]; cst = st[HDIM + tid]; }
        const int qh = (int)rintf(clamp_s(hst, -1.f, 1.f) * 127.f);
        hq8[tid] = (unsigned char)(qh & 0xFF);
    }
    __syncthreads();

    float2* pbuf2 = (float2*)pbuf;
    float prev_h = 0.0f;
    int   prev_t = -1;

    for (int i = 0; i < TC; ++i) {
        const int sl = dir ? (TC - 1 - i) : i;
        const int t  = t0 + sl;
        const h16* gp = G + (((size_t)dir*TC + sl)*NBATCH + b)*GDIM;

        const unsigned wv = ((const unsigned*)hq8)[(half << 5) | (lane & 31)];

        float g0 = 0.f, g1 = 0.f, g2 = 0.f, g3 = 0.f;
        if (tid < HDIM) {
            if (prev_t >= 0)
                out[((size_t)b*T_LEN + prev_t)*(2*HDIM) + dir*HDIM + tid] = prev_h;
            g0 = (float)gp[tid];
            g1 = (float)gp[HDIM + tid];
            g2 = (float)gp[2*HDIM + tid];
            g3 = (float)gp[3*HDIM + tid];
        }

        int accA = 0, accB = 0;
        #pragma unroll
        for (int g = 0; g < 8; ++g) {                  // same order as r18/r19: g0..g7 per row
            const int s0 = __builtin_amdgcn_readlane((int)wv, 4*g + 0);
            const int s1 = __builtin_amdgcn_readlane((int)wv, 4*g + 1);
            const int s2 = __builtin_amdgcn_readlane((int)wv, 4*g + 2);
            const int s3 = __builtin_amdgcn_readlane((int)wv, 4*g + 3);
            const uint4 wA = (g < 5) ? lw8[g*1024 + tid]
                                     : (g == 5 ? ra0 : (g == 6 ? ra1 : ra2));
            const uint4 wB = rb[g];
            accA = dot4i8(s0, (int)wA.x, accA);
            accA = dot4i8(s1, (int)wA.y, accA);
            accA = dot4i8(s2, (int)wA.z, accA);
            accA = dot4i8(s3, (int)wA.w, accA);
            accB = dot4i8(s0, (int)wB.x, accB);
            accB = dot4i8(s1, (int)wB.y, accB);
            accB = dot4i8(s2, (int)wB.z, accB);
            accB = dot4i8(s3, (int)wB.w, accB);
        }

        pbuf2[(half << 9) | (q << 6) | lane] = make_float2((float)accA * sclA, (float)accB * sclB);
        __syncthreads();

        if (tid < HDIM) {
            const float gi = g0 + pbuf[tid]            + pbuf[GDIM + tid];
            const float gf = g1 + pbuf[HDIM + tid]     + pbuf[GDIM + HDIM + tid];
            const float gg = g2 + pbuf[2*HDIM + tid]   + pbuf[GDIM + 2*HDIM + tid];
            const float go = g3 + pbuf[3*HDIM + tid]   + pbuf[GDIM + 3*HDIM + tid];
            const float c2 = sigm(gf)*cst + sigm(gi)*tanh_safe(gg);
            const float h2 = sigm(go)*tanh_safe(c2);
            hst = 0.1f*hst + 0.9f*h2;                   // zoneout (output is post-zoneout h)
            cst = 0.1f*cst + 0.9f*c2;
            prev_h = fixup(hst, 50.0f);
            prev_t = t;
            const int qh = (int)rintf(clamp_s(hst, -1.f, 1.f) * 127.f);
            hq8[tid] = (unsigned char)(qh & 0xFF);      // next step's recurrent h (int8)
        }
        __syncthreads();
    }

    if (tid < HDIM) {
        if (prev_t >= 0)
            out[((size_t)b*T_LEN + prev_t)*(2*HDIM) + dir*HDIM + tid] = prev_h;
        st[tid] = hst; st[HDIM + tid] = cst;
    }
}

extern "C" void kernel_launch(void* const* d_in, const int* in_sizes, int n_in,
                              void* d_out, int out_size, void* d_ws, size_t ws_size,
                              hipStream_t stream)
{
    (void)in_sizes; (void)n_in; (void)out_size;
    if (ws_size < 49152000) return;

    const float* x     = (const float*)d_in[0];
    const float* cw0   = (const float*)d_in[1];
    const float* cb0   = (const float*)d_in[2];
    const float* bg0   = (const float*)d_in[3];
    const float* bb0   = (const float*)d_in[4];
    const float* bm0   = (const float*)d_in[5];
    const float* bv0   = (const float*)d_in[6];
    const float* cw1   = (const float*)d_in[7];
    const float* cb1   = (const float*)d_in[8];
    const float* bg1   = (const float*)d_in[9];
    const float* bb1   = (const float*)d_in[10];
    const float* bm1   = (const float*)d_in[11];
    const float* bv1   = (const float*)d_in[12];
    const float* cw2   = (const float*)d_in[13];
    const float* cb2   = (const float*)d_in[14];
    const float* bg2   = (const float*)d_in[15];
    const float* bb2   = (const float*)d_in[16];
    const float* bm2   = (const float*)d_in[17];
    const float* bv2   = (const float*)d_in[18];
    const float* wih_f = (const float*)d_in[19];
    const float* whh_f = (const float*)d_in[20];
    const float* bih_f = (const float*)d_in[21];
    const float* bhh_f = (const float*)d_in[22];
    const float* wih_b = (const float*)d_in[23];
    const float* whh_b = (const float*)d_in[24];
    const float* bih_b = (const float*)d_in[25];
    const float* bhh_b = (const float*)d_in[26];

    char* ws = (char*)d_ws;
    char* od = (char*)d_out;
    h16*      A   = (h16*)(ws);
    h16*      G   = (h16*)(ws + 32768000);
    float*    st  = (float*)(ws + 45875200);
    unsigned* W8  = (unsigned*)(ws + 46006272);
    float*    scl = (float*)(ws + 46530560);
    h16*      Wg  = (h16*)(ws + 47054848);
    h16*      Bd  = (h16*)(od);
    h16*      Wp0 = (h16*)(od + 36000000);
    h16*      Wp1 = (h16*)(od + 36409600);
    h16*      Wp2 = (h16*)(od + 41652480);
    h16*      Xt0 = (h16*)(od + 46895360);
    float*    out = (float*)d_out;

    // packs
    pack_convw_kernel<<<dim3((5*512*80  + 255)/256), 256, 0, stream>>>(cw0, Wp0, 80);
    pack_convw_kernel<<<dim3((5*512*512 + 255)/256), 256, 0, stream>>>(cw1, Wp1, 512);
    pack_convw_kernel<<<dim3((5*512*512 + 255)/256), 256, 0, stream>>>(cw2, Wp2, 512);
    pack_wih_kernel<<<dim3(2*1024*512/256), 256, 0, stream>>>(wih_f, wih_b, Wg);
    whh_scale_kernel<<<dim3(8), 256, 0, stream>>>(whh_f, whh_b, scl);
    whh_prep_kernel<<<dim3(512), 256, 0, stream>>>(whh_f, whh_b, scl, W8);
    x0_transpose_kernel<<<dim3(4, 32), 256, 0, stream>>>(x, Xt0);

    // convs (implicit-GEMM MFMA)
    const dim3 cgrid(8, 4, 32);
    conv_mfma_kernel<<<cgrid, 512, 0, stream>>>(Xt0, Wp0, A,  cb0, bg0, bb0, bm0, bv0, 80);
    conv_mfma_kernel<<<cgrid, 512, 0, stream>>>(A,   Wp1, Bd, cb1, bg1, bb1, bm1, bv1, 512);
    conv_mfma_kernel<<<cgrid, 512, 0, stream>>>(Bd,  Wp2, A,  cb2, bg2, bb2, bm2, bv2, 512);

    for (int c = 0; c < T_LEN / TC; ++c) {
        const int t0f = c * TC;
        const int t0b = (T_LEN - TC) - c * TC;
        gates_mfma_kernel<<<dim3(2, 8, 64), 256, 0, stream>>>(A, Wg, bih_f, bhh_f, bih_b, bhh_b, G, t0f, t0b);
        lstm_chunk_kernel<<<dim3(64), 1024, 0, stream>>>(G, W8, scl, st, out, t0f, t0b, c == 0);
    }
}

// Round 22
// 1722.206 us; speedup vs baseline: 1.0225x; 1.0013x over previous
//
#include <hip/hip_runtime.h>

// Encoder: 3x [conv1d(K=5,pad2)+BN+ReLU] -> biLSTM(H=256) zoneout(0.1).  MFMA convs/gates; int8 VALU recurrence.
// r22: conv_mfma templated on CIN (compile-time 80/512) -- constant-folds staging address math
//   (v_mul chains -> shifts) and makes the cs loop a compile-time-count loop. Bit-identical math.
//   Everything else frozen at r21 (lstm: int8, 11 reg-chunks + 5 LDS-chunks).
// ws:    A f16 @0 (32,768,000) | G f16 [2][100][32][1024] @32,768,000 (13,107,200)
//        | state @45,875,200 (131,072) | W8 @46,006,272 (524,288) | scl f32[2048] @46,530,560 (8,192)
//        | Wg f16 [2][1024][512] @47,054,848 (2,097,152) -> 49,152,000 B
// d_out: Bd (conv1 out) @0 | Wp0 @36,000,000 | Wp1 @36,409,600 | Wp2 @41,652,480 | Xt0 @46,895,360

#define T_LEN 1000
#define NBATCH 32
#define CCH 512
#define HDIM 256
#define GDIM 1024
#define TC 100

typedef _Float16 h16;
typedef _Float16 h16x2 __attribute__((ext_vector_type(2)));
typedef _Float16 f16x8 __attribute__((ext_vector_type(8)));
typedef float    f32x4 __attribute__((ext_vector_type(4)));

__device__ __forceinline__ float fixup(float v, float alt){
    union { float f; unsigned u; } c; c.f = v;
    return ((c.u & 0x7f800000u) == 0x7f800000u) ? alt : v;
}
__device__ __forceinline__ float clamp_s(float v, float lo, float hi){
    return fminf(fmaxf(v, lo), hi);
}
__device__ __forceinline__ float sigm(float x){
    const float xc = clamp_s(x, -30.f, 30.f);
    return 1.0f / (1.0f + __expf(-xc));
}
__device__ __forceinline__ float tanh_safe(float x){
    const float ax = fminf(fabsf(x), 30.0f);
    const float t  = __expf(-2.0f * ax);
    const float r  = (1.0f - t) / (1.0f + t);
    return copysignf(r, x);
}
// v_dot4_i32_i8: 4 int8 MACs + i32 accumulate
__device__ __forceinline__ int dot4i8(int a, int b, int c){
#if defined(__has_builtin) && __has_builtin(__builtin_amdgcn_sdot4)
    return __builtin_amdgcn_sdot4(a, b, c, false);
#else
    int r = c;
    #pragma unroll
    for (int k = 0; k < 4; ++k) {
        const int av = (a << (24 - 8*k)) >> 24;
        const int bv = (b << (24 - 8*k)) >> 24;
        r += av * bv;
    }
    return r;
#endif
}

// ---------------- packs ----------------
__global__ __launch_bounds__(256)
void pack_convw_kernel(const float* __restrict__ cw, h16* __restrict__ Wp, int cin)
{
    const int n = blockIdx.x*256 + threadIdx.x;
    if (n >= 5*512*cin) return;
    const int k   = n / (512*cin);
    const int rem = n - k*512*cin;
    const int co  = rem / cin;
    const int ci  = rem - co*cin;
    Wp[n] = (h16)cw[((size_t)co*cin + ci)*5 + k];
}

__global__ __launch_bounds__(256)
void pack_wih_kernel(const float* __restrict__ wf, const float* __restrict__ wb, h16* __restrict__ Wg)
{
    const int n = blockIdx.x*256 + threadIdx.x;
    const float* src = (n < 1024*512) ? wf : wb;
    Wg[n] = (h16)src[n & (1024*512 - 1)];
}

// per-row |max| -> dot-scale scl[dir*1024+row] = max/(127*127)
__global__ __launch_bounds__(256)
void whh_scale_kernel(const float* __restrict__ whh_f, const float* __restrict__ whh_b,
                      float* __restrict__ scl)
{
    const int n = blockIdx.x*256 + threadIdx.x;   // 2048
    if (n >= 2048) return;
    const float* whh = (n >= 1024) ? whh_b : whh_f;
    const int row = n & 1023;
    float m = 0.f;
    for (int k = 0; k < HDIM; ++k) m = fmaxf(m, fabsf(whh[(size_t)row*HDIM + k]));
    scl[n] = fmaxf(m, 1e-8f) / 16129.0f;
}

// whh f32 -> int8 chunk-major pack (r21 mapping).
__global__ __launch_bounds__(256)
void whh_prep_kernel(const float* __restrict__ whh_f, const float* __restrict__ whh_b,
                     const float* __restrict__ scl, unsigned* __restrict__ W8)
{
    const int n = blockIdx.x * 256 + threadIdx.x;   // 131072 u32
    if (n >= 2*16*1024*4) return;
    const int dir   = n >> 16;
    const int rem   = n & 65535;
    const int chunk = rem >> 12;
    const int idx   = rem & 4095;
    const int t     = idx >> 2;
    const int e     = idx & 3;
    const float* whh = dir ? whh_b : whh_f;
    const int half = (t >> 6) & 1;
    const int qq   = t >> 7;
    const int l    = t & 63;
    const int rA   = qq*128 + 2*l;
    int row, g;
    if (chunk < 8)        { row = rA + 1; g = chunk; }
    else if (chunk < 11)  { row = rA;     g = chunk - 3; }
    else                  { row = rA;     g = chunk - 11; }
    const float inv = 1.0f / (scl[dir*1024 + row] * 127.0f);   // = 127/max
    const int k0 = 128*half + 16*g + 4*e;
    unsigned u = 0;
    #pragma unroll
    for (int j = 0; j < 4; ++j) {
        const float w = whh[(size_t)row*HDIM + k0 + j];
        int qv = (int)rintf(w * inv);
        qv = qv > 127 ? 127 : (qv < -127 ? -127 : qv);
        u |= ((unsigned)(qv & 0xFF)) << (8*j);
    }
    W8[n] = u;
}

__global__ __launch_bounds__(256)
void x0_transpose_kernel(const float* __restrict__ x, h16* __restrict__ Xt0)
{
    const int b = blockIdx.y;
    const int t = blockIdx.x*256 + threadIdx.x;
    if (t >= T_LEN) return;
    h16 v[80];
    #pragma unroll
    for (int c = 0; c < 80; ++c) v[c] = (h16)x[((size_t)b*80 + c)*T_LEN + t];
    #pragma unroll
    for (int g = 0; g < 10; ++g)
        *(f16x8*)(Xt0 + ((size_t)b*T_LEN + t)*80 + g*8) = *(const f16x8*)(v + g*8);
}

// ---------------- conv (implicit GEMM, MFMA 16x16x32 f16), CIN compile-time ----------------
template<int CIN>
__global__ __attribute__((amdgpu_flat_work_group_size(512,512), amdgpu_waves_per_eu(4,4)))
void conv_mfma_kernel(const h16* __restrict__ Xt, const h16* __restrict__ Wp,
                      h16* __restrict__ outp,
                      const float* __restrict__ cb, const float* __restrict__ bg,
                      const float* __restrict__ bb, const float* __restrict__ bm,
                      const float* __restrict__ bv)
{
    const int t0   = blockIdx.x * 128;
    const int co0  = blockIdx.y * 128;
    const int b    = blockIdx.z;
    const int tid  = threadIdx.x;
    const int lane = tid & 63;
    const int w    = tid >> 6;
    const int wm   = w >> 2;
    const int wn   = w & 3;
    const int lr   = lane & 15;
    const int lg   = lane >> 4;

    __shared__ __align__(16) h16 Xs[132*40];
    __shared__ __align__(16) h16 Ws[5*128*40];

    f32x4 acc[4][2];
    #pragma unroll
    for (int m = 0; m < 4; ++m)
        #pragma unroll
        for (int n = 0; n < 2; ++n)
            #pragma unroll
            for (int r = 0; r < 4; ++r) acc[m][n][r] = 0.f;

    constexpr int KSTEPS = (CIN + 31) >> 5;
    for (int cs = 0; cs < KSTEPS; ++cs) {
        const int c0 = cs << 5;
        for (int id = tid; id < 132*4; id += 512) {
            const int row = id >> 2, g = id & 3;
            const int t = t0 + row - 2;
            f16x8 v;
            #pragma unroll
            for (int j = 0; j < 8; ++j) v[j] = (h16)0.f;
            if (t >= 0 && t < T_LEN) {
                const int c = c0 + g*8;
                if (c + 8 <= CIN) {
                    v = *(const f16x8*)(Xt + ((size_t)b*T_LEN + t)*CIN + c);
                } else if (c < CIN) {
                    #pragma unroll
                    for (int j = 0; j < 8; ++j) if (c + j < CIN) v[j] = Xt[((size_t)b*T_LEN + t)*CIN + c + j];
                }
            }
            *(f16x8*)(Xs + row*40 + g*8) = v;
        }
        for (int id = tid; id < 5*128*4; id += 512) {
            const int k  = id >> 9;
            const int co = (id >> 2) & 127;
            const int g  = id & 3;
            const int c  = c0 + g*8;
            f16x8 v;
            #pragma unroll
            for (int j = 0; j < 8; ++j) v[j] = (h16)0.f;
            if (c + 8 <= CIN) {
                v = *(const f16x8*)(Wp + ((size_t)k*512 + co0 + co)*CIN + c);
            } else if (c < CIN) {
                #pragma unroll
                for (int j = 0; j < 8; ++j) if (c + j < CIN) v[j] = Wp[((size_t)k*512 + co0 + co)*CIN + c + j];
            }
            *(f16x8*)(Ws + (k*128 + co)*40 + g*8) = v;
        }
        __syncthreads();

        #pragma unroll
        for (int k = 0; k < 5; ++k) {
            const f16x8 b0 = *(const f16x8*)(Ws + (k*128 + wn*32 +      lr)*40 + lg*8);
            const f16x8 b1 = *(const f16x8*)(Ws + (k*128 + wn*32 + 16 + lr)*40 + lg*8);
            #pragma unroll
            for (int m = 0; m < 4; ++m) {
                const f16x8 a = *(const f16x8*)(Xs + (wm*64 + m*16 + lr + k)*40 + lg*8);
                acc[m][0] = __builtin_amdgcn_mfma_f32_16x16x32_f16(a, b0, acc[m][0], 0, 0, 0);
                acc[m][1] = __builtin_amdgcn_mfma_f32_16x16x32_f16(a, b1, acc[m][1], 0, 0, 0);
            }
        }
        __syncthreads();
    }

    #pragma unroll
    for (int nf = 0; nf < 2; ++nf) {
        const int co = co0 + wn*32 + nf*16 + lr;
        const float s  = bg[co] * rsqrtf(fmaxf(bv[co] + 1e-5f, 1e-8f));
        const float sh = (cb[co] - bm[co]) * s + bb[co];
        #pragma unroll
        for (int m = 0; m < 4; ++m) {
            #pragma unroll
            for (int r = 0; r < 4; ++r) {
                const int t = t0 + wm*64 + m*16 + lg*4 + r;
                if (t < T_LEN) {
                    const float y = fixup(clamp_s(fmaxf(acc[m][nf][r]*s + sh, 0.f), 0.f, 60000.f), 0.f);
                    outp[((size_t)b*T_LEN + t)*CCH + co] = (h16)y;
                }
            }
        }
    }
}

// ---------------- gates GEMM (MFMA), one time-chunk, both dirs ----------------
__global__ __attribute__((amdgpu_flat_work_group_size(256,256), amdgpu_waves_per_eu(4,4)))
void gates_mfma_kernel(const h16* __restrict__ Xt,
                       const h16* __restrict__ Wg,
                       const float* __restrict__ bih_f, const float* __restrict__ bhh_f,
                       const float* __restrict__ bih_b, const float* __restrict__ bhh_b,
                       h16* __restrict__ G, int t0f, int t0b)
{
    const int tt   = blockIdx.x;
    const int r0   = blockIdx.y * 128;
    const int b    = blockIdx.z & 31;
    const int dir  = blockIdx.z >> 5;
    const int t0c  = dir ? t0b : t0f;
    const int tid  = threadIdx.x;
    const int lane = tid & 63;
    const int w    = tid >> 6;
    const int lr   = lane & 15;
    const int lg   = lane >> 4;
    const float* bi = dir ? bih_b : bih_f;
    const float* bh = dir ? bhh_b : bhh_f;
    const h16* Wd = Wg + (size_t)dir*1024*512;

    __shared__ __align__(16) h16 Xs[64*40];
    __shared__ __align__(16) h16 Ws[128*40];

    f32x4 acc[4][2];
    #pragma unroll
    for (int m = 0; m < 4; ++m)
        #pragma unroll
        for (int n = 0; n < 2; ++n)
            #pragma unroll
            for (int r = 0; r < 4; ++r) acc[m][n][r] = 0.f;

    for (int cs = 0; cs < 16; ++cs) {
        const int c0 = cs << 5;
        for (int id = tid; id < 64*4; id += 256) {
            const int row = id >> 2, g = id & 3;
            int t = t0c + tt*64 + row; if (t >= T_LEN) t = T_LEN - 1;
            *(f16x8*)(Xs + row*40 + g*8) = *(const f16x8*)(Xt + ((size_t)b*T_LEN + t)*CCH + c0 + g*8);
        }
        for (int id = tid; id < 128*4; id += 256) {
            const int row = id >> 2, g = id & 3;
            *(f16x8*)(Ws + row*40 + g*8) = *(const f16x8*)(Wd + (size_t)(r0 + row)*CCH + c0 + g*8);
        }
        __syncthreads();

        const f16x8 b0 = *(const f16x8*)(Ws + (w*32 +      lr)*40 + lg*8);
        const f16x8 b1 = *(const f16x8*)(Ws + (w*32 + 16 + lr)*40 + lg*8);
        #pragma unroll
        for (int m = 0; m < 4; ++m) {
            const f16x8 a = *(const f16x8*)(Xs + (m*16 + lr)*40 + lg*8);
            acc[m][0] = __builtin_amdgcn_mfma_f32_16x16x32_f16(a, b0, acc[m][0], 0, 0, 0);
            acc[m][1] = __builtin_amdgcn_mfma_f32_16x16x32_f16(a, b1, acc[m][1], 0, 0, 0);
        }
        __syncthreads();
    }

    #pragma unroll
    for (int nf = 0; nf < 2; ++nf) {
        const int row = r0 + w*32 + nf*16 + lr;
        const float bias = bi[row] + bh[row];
        #pragma unroll
        for (int m = 0; m < 4; ++m) {
            #pragma unroll
            for (int r = 0; r < 4; ++r) {
                const int tl = tt*64 + m*16 + lg*4 + r;
                if (tl < TC)
                    G[(((size_t)dir*TC + tl)*NBATCH + b)*GDIM + row]
                        = (h16)fixup(clamp_s(acc[m][nf][r] + bias, -60000.f, 60000.f), 0.f);
            }
        }
    }
}

// ---------------- persistent biLSTM recurrence: int8, 11 reg-chunks + 5 LDS-chunks (r21) ----------------
__global__ __attribute__((amdgpu_flat_work_group_size(1024, 1024), amdgpu_waves_per_eu(4, 4)))
void lstm_chunk_kernel(const h16* __restrict__ G,
                       const unsigned* __restrict__ W8,
                       const float* __restrict__ scl,
                       float* __restrict__ state,
                       float* __restrict__ out,
                       int t0f, int t0b, int first)
{
    const int tid  = threadIdx.x;
    const int lane = tid & 63;
    const int half = (tid >> 6) & 1;
    const int q    = tid >> 7;
    const int dir  = blockIdx.x >> 5;
    const int b    = blockIdx.x & 31;
    const int t0   = dir ? t0b : t0f;
    float* st = state + ((size_t)(dir*NBATCH + b))*2*HDIM;
    const uint4* Wg8 = (const uint4*)W8 + (size_t)dir*16384;

    __shared__ __align__(16) uint4 lw8[5*1024];        // 80 KB: rowA g0..4
    __shared__ __align__(4)  unsigned char hq8[256];   // h int8
    __shared__ float pbuf[2*GDIM];                     // 8 KB

    uint4 rb[8];
    #pragma unroll
    for (int g = 0; g < 8; ++g) rb[g] = Wg8[g*1024 + tid];     // rowB g0..7
    uint4 ra0 = Wg8[8*1024 + tid];                             // rowA g5
    uint4 ra1 = Wg8[9*1024 + tid];                             // rowA g6
    uint4 ra2 = Wg8[10*1024 + tid];                            // rowA g7

    #pragma unroll
    for (int s = 0; s < 5; ++s)
        lw8[s*1024 + tid] = Wg8[(11 + s)*1024 + tid];          // rowA g0..4 -> LDS

    const int rA = q*128 + 2*lane;
    const float sclA = scl[dir*1024 + rA];
    const float sclB = scl[dir*1024 + rA + 1];

    float hst = 0.0f, cst = 0.0f;
    if (tid < HDIM) {
        if (!first) { hst = st[tid]; cst = st[HDIM + tid]; }
        const int qh = (int)rintf(clamp_s(hst, -1.f, 1.f) * 127.f);
        hq8[tid] = (unsigned char)(qh & 0xFF);
    }
    __syncthreads();

    float2* pbuf2 = (float2*)pbuf;
    float prev_h = 0.0f;
    int   prev_t = -1;

    for (int i = 0; i < TC; ++i) {
        const int sl = dir ? (TC - 1 - i) : i;
        const int t  = t0 + sl;
        const h16* gp = G + (((size_t)dir*TC + sl)*NBATCH + b)*GDIM;

        const unsigned wv = ((const unsigned*)hq8)[(half << 5) | (lane & 31)];

        float g0 = 0.f, g1 = 0.f, g2 = 0.f, g3 = 0.f;
        if (tid < HDIM) {
            if (prev_t >= 0)
                out[((size_t)b*T_LEN + prev_t)*(2*HDIM) + dir*HDIM + tid] = prev_h;
            g0 = (float)gp[tid];
            g1 = (float)gp[HDIM + tid];
            g2 = (float)gp[2*HDIM + tid];
            g3 = (float)gp[3*HDIM + tid];
        }

        int accA = 0, accB = 0;
        #pragma unroll
        for (int g = 0; g < 8; ++g) {                  // same order as r18/r19: g0..g7 per row
            const int s0 = __builtin_amdgcn_readlane((int)wv, 4*g + 0);
            const int s1 = __builtin_amdgcn_readlane((int)wv, 4*g + 1);
            const int s2 = __builtin_amdgcn_readlane((int)wv, 4*g + 2);
            const int s3 = __builtin_amdgcn_readlane((int)wv, 4*g + 3);
            const uint4 wA = (g < 5) ? lw8[g*1024 + tid]
                                     : (g == 5 ? ra0 : (g == 6 ? ra1 : ra2));
            const uint4 wB = rb[g];
            accA = dot4i8(s0, (int)wA.x, accA);
            accA = dot4i8(s1, (int)wA.y, accA);
            accA = dot4i8(s2, (int)wA.z, accA);
            accA = dot4i8(s3, (int)wA.w, accA);
            accB = dot4i8(s0, (int)wB.x, accB);
            accB = dot4i8(s1, (int)wB.y, accB);
            accB = dot4i8(s2, (int)wB.z, accB);
            accB = dot4i8(s3, (int)wB.w, accB);
        }

        pbuf2[(half << 9) | (q << 6) | lane] = make_float2((float)accA * sclA, (float)accB * sclB);
        __syncthreads();

        if (tid < HDIM) {
            const float gi = g0 + pbuf[tid]            + pbuf[GDIM + tid];
            const float gf = g1 + pbuf[HDIM + tid]     + pbuf[GDIM + HDIM + tid];
            const float gg = g2 + pbuf[2*HDIM + tid]   + pbuf[GDIM + 2*HDIM + tid];
            const float go = g3 + pbuf[3*HDIM + tid]   + pbuf[GDIM + 3*HDIM + tid];
            const float c2 = sigm(gf)*cst + sigm(gi)*tanh_safe(gg);
            const float h2 = sigm(go)*tanh_safe(c2);
            hst = 0.1f*hst + 0.9f*h2;                   // zoneout (output is post-zoneout h)
            cst = 0.1f*cst + 0.9f*c2;
            prev_h = fixup(hst, 50.0f);
            prev_t = t;
            const int qh = (int)rintf(clamp_s(hst, -1.f, 1.f) * 127.f);
            hq8[tid] = (unsigned char)(qh & 0xFF);      // next step's recurrent h (int8)
        }
        __syncthreads();
    }

    if (tid < HDIM) {
        if (prev_t >= 0)
            out[((size_t)b*T_LEN + prev_t)*(2*HDIM) + dir*HDIM + tid] = prev_h;
        st[tid] = hst; st[HDIM + tid] = cst;
    }
}

extern "C" void kernel_launch(void* const* d_in, const int* in_sizes, int n_in,
                              void* d_out, int out_size, void* d_ws, size_t ws_size,
                              hipStream_t stream)
{
    (void)in_sizes; (void)n_in; (void)out_size;
    if (ws_size < 49152000) return;

    const float* x     = (const float*)d_in[0];
    const float* cw0   = (const float*)d_in[1];
    const float* cb0   = (const float*)d_in[2];
    const float* bg0   = (const float*)d_in[3];
    const float* bb0   = (const float*)d_in[4];
    const float* bm0   = (const float*)d_in[5];
    const float* bv0   = (const float*)d_in[6];
    const float* cw1   = (const float*)d_in[7];
    const float* cb1   = (const float*)d_in[8];
    const float* bg1   = (const float*)d_in[9];
    const float* bb1   = (const float*)d_in[10];
    const float* bm1   = (const float*)d_in[11];
    const float* bv1   = (const float*)d_in[12];
    const float* cw2   = (const float*)d_in[13];
    const float* cb2   = (const float*)d_in[14];
    const float* bg2   = (const float*)d_in[15];
    const float* bb2   = (const float*)d_in[16];
    const float* bm2   = (const float*)d_in[17];
    const float* bv2   = (const float*)d_in[18];
    const float* wih_f = (const float*)d_in[19];
    const float* whh_f = (const float*)d_in[20];
    const float* bih_f = (const float*)d_in[21];
    const float* bhh_f = (const float*)d_in[22];
    const float* wih_b = (const float*)d_in[23];
    const float* whh_b = (const float*)d_in[24];
    const float* bih_b = (const float*)d_in[25];
    const float* bhh_b = (const float*)d_in[26];

    char* ws = (char*)d_ws;
    char* od = (char*)d_out;
    h16*      A   = (h16*)(ws);
    h16*      G   = (h16*)(ws + 32768000);
    float*    st  = (float*)(ws + 45875200);
    unsigned* W8  = (unsigned*)(ws + 46006272);
    float*    scl = (float*)(ws + 46530560);
    h16*      Wg  = (h16*)(ws + 47054848);
    h16*      Bd  = (h16*)(od);
    h16*      Wp0 = (h16*)(od + 36000000);
    h16*      Wp1 = (h16*)(od + 36409600);
    h16*      Wp2 = (h16*)(od + 41652480);
    h16*      Xt0 = (h16*)(od + 46895360);
    float*    out = (float*)d_out;

    // packs
    pack_convw_kernel<<<dim3((5*512*80  + 255)/256), 256, 0, stream>>>(cw0, Wp0, 80);
    pack_convw_kernel<<<dim3((5*512*512 + 255)/256), 256, 0, stream>>>(cw1, Wp1, 512);
    pack_convw_kernel<<<dim3((5*512*512 + 255)/256), 256, 0, stream>>>(cw2, Wp2, 512);
    pack_wih_kernel<<<dim3(2*1024*512/256), 256, 0, stream>>>(wih_f, wih_b, Wg);
    whh_scale_kernel<<<dim3(8), 256, 0, stream>>>(whh_f, whh_b, scl);
    whh_prep_kernel<<<dim3(512), 256, 0, stream>>>(whh_f, whh_b, scl, W8);
    x0_transpose_kernel<<<dim3(4, 32), 256, 0, stream>>>(x, Xt0);

    // convs (implicit-GEMM MFMA, compile-time CIN)
    const dim3 cgrid(8, 4, 32);
    conv_mfma_kernel<80> <<<cgrid, 512, 0, stream>>>(Xt0, Wp0, A,  cb0, bg0, bb0, bm0, bv0);
    conv_mfma_kernel<512><<<cgrid, 512, 0, stream>>>(A,   Wp1, Bd, cb1, bg1, bb1, bm1, bv1);
    conv_mfma_kernel<512><<<cgrid, 512, 0, stream>>>(Bd,  Wp2, A,  cb2, bg2, bb2, bm2, bv2);

    for (int c = 0; c < T_LEN / TC; ++c) {
        const int t0f = c * TC;
        const int t0b = (T_LEN - TC) - c * TC;
        gates_mfma_kernel<<<dim3(2, 8, 64), 256, 0, stream>>>(A, Wg, bih_f, bhh_f, bih_b, bhh_b, G, t0f, t0b);
        lstm_chunk_kernel<<<dim3(64), 1024, 0, stream>>>(G, W8, scl, st, out, t0f, t0b, c == 0);
    }
}

// Round 23
// 1665.497 us; speedup vs baseline: 1.0573x; 1.0340x over previous
//
#include <hip/hip_runtime.h>

// Encoder: 3x [conv1d(K=5,pad2)+BN+ReLU] -> biLSTM(H=256) zoneout(0.1).  MFMA convs/gates; int8 VALU recurrence.
// r23: conv wave-tile 64x64 (4m x 4n frags): 8 ds_read_b128 per 16 MFMA (0.5 reads/MFMA, was 0.75)
//   -- LDS-read-issue bound kernel, -33% read issue. Block tile 256t x 128co, 8 waves (4x2).
//   Accumulation order per output unchanged -> bit-identical (absmax must stay 0.01025391).
//   Gates/lstm frozen at r22 (lstm: int8, 11 reg-chunks + 5 LDS-chunks).
// ws:    A f16 @0 (32,768,000) | G f16 [2][100][32][1024] @32,768,000 (13,107,200)
//        | state @45,875,200 (131,072) | W8 @46,006,272 (524,288) | scl f32[2048] @46,530,560 (8,192)
//        | Wg f16 [2][1024][512] @47,054,848 (2,097,152) -> 49,152,000 B
// d_out: Bd (conv1 out) @0 | Wp0 @36,000,000 | Wp1 @36,409,600 | Wp2 @41,652,480 | Xt0 @46,895,360

#define T_LEN 1000
#define NBATCH 32
#define CCH 512
#define HDIM 256
#define GDIM 1024
#define TC 100

typedef _Float16 h16;
typedef _Float16 h16x2 __attribute__((ext_vector_type(2)));
typedef _Float16 f16x8 __attribute__((ext_vector_type(8)));
typedef float    f32x4 __attribute__((ext_vector_type(4)));

__device__ __forceinline__ float fixup(float v, float alt){
    union { float f; unsigned u; } c; c.f = v;
    return ((c.u & 0x7f800000u) == 0x7f800000u) ? alt : v;
}
__device__ __forceinline__ float clamp_s(float v, float lo, float hi){
    return fminf(fmaxf(v, lo), hi);
}
__device__ __forceinline__ float sigm(float x){
    const float xc = clamp_s(x, -30.f, 30.f);
    return 1.0f / (1.0f + __expf(-xc));
}
__device__ __forceinline__ float tanh_safe(float x){
    const float ax = fminf(fabsf(x), 30.0f);
    const float t  = __expf(-2.0f * ax);
    const float r  = (1.0f - t) / (1.0f + t);
    return copysignf(r, x);
}
// v_dot4_i32_i8: 4 int8 MACs + i32 accumulate
__device__ __forceinline__ int dot4i8(int a, int b, int c){
#if defined(__has_builtin) && __has_builtin(__builtin_amdgcn_sdot4)
    return __builtin_amdgcn_sdot4(a, b, c, false);
#else
    int r = c;
    #pragma unroll
    for (int k = 0; k < 4; ++k) {
        const int av = (a << (24 - 8*k)) >> 24;
        const int bv = (b << (24 - 8*k)) >> 24;
        r += av * bv;
    }
    return r;
#endif
}

// ---------------- packs ----------------
__global__ __launch_bounds__(256)
void pack_convw_kernel(const float* __restrict__ cw, h16* __restrict__ Wp, int cin)
{
    const int n = blockIdx.x*256 + threadIdx.x;
    if (n >= 5*512*cin) return;
    const int k   = n / (512*cin);
    const int rem = n - k*512*cin;
    const int co  = rem / cin;
    const int ci  = rem - co*cin;
    Wp[n] = (h16)cw[((size_t)co*cin + ci)*5 + k];
}

__global__ __launch_bounds__(256)
void pack_wih_kernel(const float* __restrict__ wf, const float* __restrict__ wb, h16* __restrict__ Wg)
{
    const int n = blockIdx.x*256 + threadIdx.x;
    const float* src = (n < 1024*512) ? wf : wb;
    Wg[n] = (h16)src[n & (1024*512 - 1)];
}

// per-row |max| -> dot-scale scl[dir*1024+row] = max/(127*127)
__global__ __launch_bounds__(256)
void whh_scale_kernel(const float* __restrict__ whh_f, const float* __restrict__ whh_b,
                      float* __restrict__ scl)
{
    const int n = blockIdx.x*256 + threadIdx.x;   // 2048
    if (n >= 2048) return;
    const float* whh = (n >= 1024) ? whh_b : whh_f;
    const int row = n & 1023;
    float m = 0.f;
    for (int k = 0; k < HDIM; ++k) m = fmaxf(m, fabsf(whh[(size_t)row*HDIM + k]));
    scl[n] = fmaxf(m, 1e-8f) / 16129.0f;
}

// whh f32 -> int8 chunk-major pack (r21 mapping).
__global__ __launch_bounds__(256)
void whh_prep_kernel(const float* __restrict__ whh_f, const float* __restrict__ whh_b,
                     const float* __restrict__ scl, unsigned* __restrict__ W8)
{
    const int n = blockIdx.x * 256 + threadIdx.x;   // 131072 u32
    if (n >= 2*16*1024*4) return;
    const int dir   = n >> 16;
    const int rem   = n & 65535;
    const int chunk = rem >> 12;
    const int idx   = rem & 4095;
    const int t     = idx >> 2;
    const int e     = idx & 3;
    const float* whh = dir ? whh_b : whh_f;
    const int half = (t >> 6) & 1;
    const int qq   = t >> 7;
    const int l    = t & 63;
    const int rA   = qq*128 + 2*l;
    int row, g;
    if (chunk < 8)        { row = rA + 1; g = chunk; }
    else if (chunk < 11)  { row = rA;     g = chunk - 3; }
    else                  { row = rA;     g = chunk - 11; }
    const float inv = 1.0f / (scl[dir*1024 + row] * 127.0f);   // = 127/max
    const int k0 = 128*half + 16*g + 4*e;
    unsigned u = 0;
    #pragma unroll
    for (int j = 0; j < 4; ++j) {
        const float w = whh[(size_t)row*HDIM + k0 + j];
        int qv = (int)rintf(w * inv);
        qv = qv > 127 ? 127 : (qv < -127 ? -127 : qv);
        u |= ((unsigned)(qv & 0xFF)) << (8*j);
    }
    W8[n] = u;
}

__global__ __launch_bounds__(256)
void x0_transpose_kernel(const float* __restrict__ x, h16* __restrict__ Xt0)
{
    const int b = blockIdx.y;
    const int t = blockIdx.x*256 + threadIdx.x;
    if (t >= T_LEN) return;
    h16 v[80];
    #pragma unroll
    for (int c = 0; c < 80; ++c) v[c] = (h16)x[((size_t)b*80 + c)*T_LEN + t];
    #pragma unroll
    for (int g = 0; g < 10; ++g)
        *(f16x8*)(Xt0 + ((size_t)b*T_LEN + t)*80 + g*8) = *(const f16x8*)(v + g*8);
}

// ---------------- conv (implicit GEMM, MFMA 16x16x32 f16), 64x64 wave tile ----------------
// Block 512 thr / 8 waves as 4(m) x 2(n); block tile 256t x 128co; wave tile 64t x 64co (4x4 frags).
// Per k: 4 B-reads + 4 A-reads feed 16 MFMAs (0.5 reads/MFMA).
template<int CIN>
__global__ __attribute__((amdgpu_flat_work_group_size(512,512), amdgpu_waves_per_eu(2,4)))
void conv_mfma_kernel(const h16* __restrict__ Xt, const h16* __restrict__ Wp,
                      h16* __restrict__ outp,
                      const float* __restrict__ cb, const float* __restrict__ bg,
                      const float* __restrict__ bb, const float* __restrict__ bm,
                      const float* __restrict__ bv)
{
    const int t0   = blockIdx.x * 256;
    const int co0  = blockIdx.y * 128;
    const int b    = blockIdx.z;
    const int tid  = threadIdx.x;
    const int lane = tid & 63;
    const int w    = tid >> 6;
    const int wm   = w >> 1;        // 0..3  (64t each)
    const int wn   = w & 1;         // 0..1  (64co each)
    const int lr   = lane & 15;
    const int lg   = lane >> 4;

    __shared__ __align__(16) h16 Xs[260*40];     // rows t0-2 .. t0+257, pitch 40
    __shared__ __align__(16) h16 Ws[5*128*40];   // [k][co][ci-tile], pitch 40

    f32x4 acc[4][4];
    #pragma unroll
    for (int m = 0; m < 4; ++m)
        #pragma unroll
        for (int n = 0; n < 4; ++n)
            #pragma unroll
            for (int r = 0; r < 4; ++r) acc[m][n][r] = 0.f;

    constexpr int KSTEPS = (CIN + 31) >> 5;
    for (int cs = 0; cs < KSTEPS; ++cs) {
        const int c0 = cs << 5;
        for (int id = tid; id < 260*4; id += 512) {
            const int row = id >> 2, g = id & 3;
            const int t = t0 + row - 2;
            f16x8 v;
            #pragma unroll
            for (int j = 0; j < 8; ++j) v[j] = (h16)0.f;
            if (t >= 0 && t < T_LEN) {
                const int c = c0 + g*8;
                if (c + 8 <= CIN) {
                    v = *(const f16x8*)(Xt + ((size_t)b*T_LEN + t)*CIN + c);
                } else if (c < CIN) {
                    #pragma unroll
                    for (int j = 0; j < 8; ++j) if (c + j < CIN) v[j] = Xt[((size_t)b*T_LEN + t)*CIN + c + j];
                }
            }
            *(f16x8*)(Xs + row*40 + g*8) = v;
        }
        for (int id = tid; id < 5*128*4; id += 512) {
            const int k  = id >> 9;
            const int co = (id >> 2) & 127;
            const int g  = id & 3;
            const int c  = c0 + g*8;
            f16x8 v;
            #pragma unroll
            for (int j = 0; j < 8; ++j) v[j] = (h16)0.f;
            if (c + 8 <= CIN) {
                v = *(const f16x8*)(Wp + ((size_t)k*512 + co0 + co)*CIN + c);
            } else if (c < CIN) {
                #pragma unroll
                for (int j = 0; j < 8; ++j) if (c + j < CIN) v[j] = Wp[((size_t)k*512 + co0 + co)*CIN + c + j];
            }
            *(f16x8*)(Ws + (k*128 + co)*40 + g*8) = v;
        }
        __syncthreads();

        #pragma unroll
        for (int k = 0; k < 5; ++k) {
            f16x8 bfr[4];
            #pragma unroll
            for (int nf = 0; nf < 4; ++nf)
                bfr[nf] = *(const f16x8*)(Ws + (k*128 + wn*64 + nf*16 + lr)*40 + lg*8);
            #pragma unroll
            for (int m = 0; m < 4; ++m) {
                const f16x8 a = *(const f16x8*)(Xs + (wm*64 + m*16 + lr + k)*40 + lg*8);
                #pragma unroll
                for (int nf = 0; nf < 4; ++nf)
                    acc[m][nf] = __builtin_amdgcn_mfma_f32_16x16x32_f16(a, bfr[nf], acc[m][nf], 0, 0, 0);
            }
        }
        __syncthreads();
    }

    #pragma unroll
    for (int nf = 0; nf < 4; ++nf) {
        const int co = co0 + wn*64 + nf*16 + lr;
        const float s  = bg[co] * rsqrtf(fmaxf(bv[co] + 1e-5f, 1e-8f));
        const float sh = (cb[co] - bm[co]) * s + bb[co];
        #pragma unroll
        for (int m = 0; m < 4; ++m) {
            #pragma unroll
            for (int r = 0; r < 4; ++r) {
                const int t = t0 + wm*64 + m*16 + lg*4 + r;
                if (t < T_LEN) {
                    const float y = fixup(clamp_s(fmaxf(acc[m][nf][r]*s + sh, 0.f), 0.f, 60000.f), 0.f);
                    outp[((size_t)b*T_LEN + t)*CCH + co] = (h16)y;
                }
            }
        }
    }
}

// ---------------- gates GEMM (MFMA), one time-chunk, both dirs (r22, frozen) ----------------
__global__ __attribute__((amdgpu_flat_work_group_size(256,256), amdgpu_waves_per_eu(4,4)))
void gates_mfma_kernel(const h16* __restrict__ Xt,
                       const h16* __restrict__ Wg,
                       const float* __restrict__ bih_f, const float* __restrict__ bhh_f,
                       const float* __restrict__ bih_b, const float* __restrict__ bhh_b,
                       h16* __restrict__ G, int t0f, int t0b)
{
    const int tt   = blockIdx.x;
    const int r0   = blockIdx.y * 128;
    const int b    = blockIdx.z & 31;
    const int dir  = blockIdx.z >> 5;
    const int t0c  = dir ? t0b : t0f;
    const int tid  = threadIdx.x;
    const int lane = tid & 63;
    const int w    = tid >> 6;
    const int lr   = lane & 15;
    const int lg   = lane >> 4;
    const float* bi = dir ? bih_b : bih_f;
    const float* bh = dir ? bhh_b : bhh_f;
    const h16* Wd = Wg + (size_t)dir*1024*512;

    __shared__ __align__(16) h16 Xs[64*40];
    __shared__ __align__(16) h16 Ws[128*40];

    f32x4 acc[4][2];
    #pragma unroll
    for (int m = 0; m < 4; ++m)
        #pragma unroll
        for (int n = 0; n < 2; ++n)
            #pragma unroll
            for (int r = 0; r < 4; ++r) acc[m][n][r] = 0.f;

    for (int cs = 0; cs < 16; ++cs) {
        const int c0 = cs << 5;
        for (int id = tid; id < 64*4; id += 256) {
            const int row = id >> 2, g = id & 3;
            int t = t0c + tt*64 + row; if (t >= T_LEN) t = T_LEN - 1;
            *(f16x8*)(Xs + row*40 + g*8) = *(const f16x8*)(Xt + ((size_t)b*T_LEN + t)*CCH + c0 + g*8);
        }
        for (int id = tid; id < 128*4; id += 256) {
            const int row = id >> 2, g = id & 3;
            *(f16x8*)(Ws + row*40 + g*8) = *(const f16x8*)(Wd + (size_t)(r0 + row)*CCH + c0 + g*8);
        }
        __syncthreads();

        const f16x8 b0 = *(const f16x8*)(Ws + (w*32 +      lr)*40 + lg*8);
        const f16x8 b1 = *(const f16x8*)(Ws + (w*32 + 16 + lr)*40 + lg*8);
        #pragma unroll
        for (int m = 0; m < 4; ++m) {
            const f16x8 a = *(const f16x8*)(Xs + (m*16 + lr)*40 + lg*8);
            acc[m][0] = __builtin_amdgcn_mfma_f32_16x16x32_f16(a, b0, acc[m][0], 0, 0, 0);
            acc[m][1] = __builtin_amdgcn_mfma_f32_16x16x32_f16(a, b1, acc[m][1], 0, 0, 0);
        }
        __syncthreads();
    }

    #pragma unroll
    for (int nf = 0; nf < 2; ++nf) {
        const int row = r0 + w*32 + nf*16 + lr;
        const float bias = bi[row] + bh[row];
        #pragma unroll
        for (int m = 0; m < 4; ++m) {
            #pragma unroll
            for (int r = 0; r < 4; ++r) {
                const int tl = tt*64 + m*16 + lg*4 + r;
                if (tl < TC)
                    G[(((size_t)dir*TC + tl)*NBATCH + b)*GDIM + row]
                        = (h16)fixup(clamp_s(acc[m][nf][r] + bias, -60000.f, 60000.f), 0.f);
            }
        }
    }
}

// ---------------- persistent biLSTM recurrence: int8, 11 reg-chunks + 5 LDS-chunks (r21, frozen) --------
__global__ __attribute__((amdgpu_flat_work_group_size(1024, 1024), amdgpu_waves_per_eu(4, 4)))
void lstm_chunk_kernel(const h16* __restrict__ G,
                       const unsigned* __restrict__ W8,
                       const float* __restrict__ scl,
                       float* __restrict__ state,
                       float* __restrict__ out,
                       int t0f, int t0b, int first)
{
    const int tid  = threadIdx.x;
    const int lane = tid & 63;
    const int half = (tid >> 6) & 1;
    const int q    = tid >> 7;
    const int dir  = blockIdx.x >> 5;
    const int b    = blockIdx.x & 31;
    const int t0   = dir ? t0b : t0f;
    float* st = state + ((size_t)(dir*NBATCH + b))*2*HDIM;
    const uint4* Wg8 = (const uint4*)W8 + (size_t)dir*16384;

    __shared__ __align__(16) uint4 lw8[5*1024];        // 80 KB: rowA g0..4
    __shared__ __align__(4)  unsigned char hq8[256];   // h int8
    __shared__ float pbuf[2*GDIM];                     // 8 KB

    uint4 rb[8];
    #pragma unroll
    for (int g = 0; g < 8; ++g) rb[g] = Wg8[g*1024 + tid];     // rowB g0..7
    uint4 ra0 = Wg8[8*1024 + tid];                             // rowA g5
    uint4 ra1 = Wg8[9*1024 + tid];                             // rowA g6
    uint4 ra2 = Wg8[10*1024 + tid];                            // rowA g7

    #pragma unroll
    for (int s = 0; s < 5; ++s)
        lw8[s*1024 + tid] = Wg8[(11 + s)*1024 + tid];          // rowA g0..4 -> LDS

    const int rA = q*128 + 2*lane;
    const float sclA = scl[dir*1024 + rA];
    const float sclB = scl[dir*1024 + rA + 1];

    float hst = 0.0f, cst = 0.0f;
    if (tid < HDIM) {
        if (!first) { hst = st[tid]; cst = st[HDIM + tid]; }
        const int qh = (int)rintf(clamp_s(hst, -1.f, 1.f) * 127.f);
        hq8[tid] = (unsigned char)(qh & 0xFF);
    }
    __syncthreads();

    float2* pbuf2 = (float2*)pbuf;
    float prev_h = 0.0f;
    int   prev_t = -1;

    for (int i = 0; i < TC; ++i) {
        const int sl = dir ? (TC - 1 - i) : i;
        const int t  = t0 + sl;
        const h16* gp = G + (((size_t)dir*TC + sl)*NBATCH + b)*GDIM;

        const unsigned wv = ((const unsigned*)hq8)[(half << 5) | (lane & 31)];

        float g0 = 0.f, g1 = 0.f, g2 = 0.f, g3 = 0.f;
        if (tid < HDIM) {
            if (prev_t >= 0)
                out[((size_t)b*T_LEN + prev_t)*(2*HDIM) + dir*HDIM + tid] = prev_h;
            g0 = (float)gp[tid];
            g1 = (float)gp[HDIM + tid];
            g2 = (float)gp[2*HDIM + tid];
            g3 = (float)gp[3*HDIM + tid];
        }

        int accA = 0, accB = 0;
        #pragma unroll
        for (int g = 0; g < 8; ++g) {                  // same order as r18/r19: g0..g7 per row
            const int s0 = __builtin_amdgcn_readlane((int)wv, 4*g + 0);
            const int s1 = __builtin_amdgcn_readlane((int)wv, 4*g + 1);
            const int s2 = __builtin_amdgcn_readlane((int)wv, 4*g + 2);
            const int s3 = __builtin_amdgcn_readlane((int)wv, 4*g + 3);
            const uint4 wA = (g < 5) ? lw8[g*1024 + tid]
                                     : (g == 5 ? ra0 : (g == 6 ? ra1 : ra2));
            const uint4 wB = rb[g];
            accA = dot4i8(s0, (int)wA.x, accA);
            accA = dot4i8(s1, (int)wA.y, accA);
            accA = dot4i8(s2, (int)wA.z, accA);
            accA = dot4i8(s3, (int)wA.w, accA);
            accB = dot4i8(s0, (int)wB.x, accB);
            accB = dot4i8(s1, (int)wB.y, accB);
            accB = dot4i8(s2, (int)wB.z, accB);
            accB = dot4i8(s3, (int)wB.w, accB);
        }

        pbuf2[(half << 9) | (q << 6) | lane] = make_float2((float)accA * sclA, (float)accB * sclB);
        __syncthreads();

        if (tid < HDIM) {
            const float gi = g0 + pbuf[tid]            + pbuf[GDIM + tid];
            const float gf = g1 + pbuf[HDIM + tid]     + pbuf[GDIM + HDIM + tid];
            const float gg = g2 + pbuf[2*HDIM + tid]   + pbuf[GDIM + 2*HDIM + tid];
            const float go = g3 + pbuf[3*HDIM + tid]   + pbuf[GDIM + 3*HDIM + tid];
            const float c2 = sigm(gf)*cst + sigm(gi)*tanh_safe(gg);
            const float h2 = sigm(go)*tanh_safe(c2);
            hst = 0.1f*hst + 0.9f*h2;                   // zoneout (output is post-zoneout h)
            cst = 0.1f*cst + 0.9f*c2;
            prev_h = fixup(hst, 50.0f);
            prev_t = t;
            const int qh = (int)rintf(clamp_s(hst, -1.f, 1.f) * 127.f);
            hq8[tid] = (unsigned char)(qh & 0xFF);      // next step's recurrent h (int8)
        }
        __syncthreads();
    }

    if (tid < HDIM) {
        if (prev_t >= 0)
            out[((size_t)b*T_LEN + prev_t)*(2*HDIM) + dir*HDIM + tid] = prev_h;
        st[tid] = hst; st[HDIM + tid] = cst;
    }
}

extern "C" void kernel_launch(void* const* d_in, const int* in_sizes, int n_in,
                              void* d_out, int out_size, void* d_ws, size_t ws_size,
                              hipStream_t stream)
{
    (void)in_sizes; (void)n_in; (void)out_size;
    if (ws_size < 49152000) return;

    const float* x     = (const float*)d_in[0];
    const float* cw0   = (const float*)d_in[1];
    const float* cb0   = (const float*)d_in[2];
    const float* bg0   = (const float*)d_in[3];
    const float* bb0   = (const float*)d_in[4];
    const float* bm0   = (const float*)d_in[5];
    const float* bv0   = (const float*)d_in[6];
    const float* cw1   = (const float*)d_in[7];
    const float* cb1   = (const float*)d_in[8];
    const float* bg1   = (const float*)d_in[9];
    const float* bb1   = (const float*)d_in[10];
    const float* bm1   = (const float*)d_in[11];
    const float* bv1   = (const float*)d_in[12];
    const float* cw2   = (const float*)d_in[13];
    const float* cb2   = (const float*)d_in[14];
    const float* bg2   = (const float*)d_in[15];
    const float* bb2   = (const float*)d_in[16];
    const float* bm2   = (const float*)d_in[17];
    const float* bv2   = (const float*)d_in[18];
    const float* wih_f = (const float*)d_in[19];
    const float* whh_f = (const float*)d_in[20];
    const float* bih_f = (const float*)d_in[21];
    const float* bhh_f = (const float*)d_in[22];
    const float* wih_b = (const float*)d_in[23];
    const float* whh_b = (const float*)d_in[24];
    const float* bih_b = (const float*)d_in[25];
    const float* bhh_b = (const float*)d_in[26];

    char* ws = (char*)d_ws;
    char* od = (char*)d_out;
    h16*      A   = (h16*)(ws);
    h16*      G   = (h16*)(ws + 32768000);
    float*    st  = (float*)(ws + 45875200);
    unsigned* W8  = (unsigned*)(ws + 46006272);
    float*    scl = (float*)(ws + 46530560);
    h16*      Wg  = (h16*)(ws + 47054848);
    h16*      Bd  = (h16*)(od);
    h16*      Wp0 = (h16*)(od + 36000000);
    h16*      Wp1 = (h16*)(od + 36409600);
    h16*      Wp2 = (h16*)(od + 41652480);
    h16*      Xt0 = (h16*)(od + 46895360);
    float*    out = (float*)d_out;

    // packs
    pack_convw_kernel<<<dim3((5*512*80  + 255)/256), 256, 0, stream>>>(cw0, Wp0, 80);
    pack_convw_kernel<<<dim3((5*512*512 + 255)/256), 256, 0, stream>>>(cw1, Wp1, 512);
    pack_convw_kernel<<<dim3((5*512*512 + 255)/256), 256, 0, stream>>>(cw2, Wp2, 512);
    pack_wih_kernel<<<dim3(2*1024*512/256), 256, 0, stream>>>(wih_f, wih_b, Wg);
    whh_scale_kernel<<<dim3(8), 256, 0, stream>>>(whh_f, whh_b, scl);
    whh_prep_kernel<<<dim3(512), 256, 0, stream>>>(whh_f, whh_b, scl, W8);
    x0_transpose_kernel<<<dim3(4, 32), 256, 0, stream>>>(x, Xt0);

    // convs (implicit-GEMM MFMA, 64x64 wave tile)
    const dim3 cgrid(4, 4, 32);   // 256t-tiles x 128co-tiles x batch
    conv_mfma_kernel<80> <<<cgrid, 512, 0, stream>>>(Xt0, Wp0, A,  cb0, bg0, bb0, bm0, bv0);
    conv_mfma_kernel<512><<<cgrid, 512, 0, stream>>>(A,   Wp1, Bd, cb1, bg1, bb1, bm1, bv1);
    conv_mfma_kernel<512><<<cgrid, 512, 0, stream>>>(Bd,  Wp2, A,  cb2, bg2, bb2, bm2, bv2);

    for (int c = 0; c < T_LEN / TC; ++c) {
        const int t0f = c * TC;
        const int t0b = (T_LEN - TC) - c * TC;
        gates_mfma_kernel<<<dim3(2, 8, 64), 256, 0, stream>>>(A, Wg, bih_f, bhh_f, bih_b, bhh_b, G, t0f, t0b);
        lstm_chunk_kernel<<<dim3(64), 1024, 0, stream>>>(G, W8, scl, st, out, t0f, t0b, c == 0);
    }
}

// Round 24
// 1432.021 us; speedup vs baseline: 1.2297x; 1.1630x over previous
//
#include <hip/hip_runtime.h>

// Encoder: 3x [conv1d(K=5,pad2)+BN+ReLU] -> biLSTM(H=256) zoneout(0.1).  MFMA convs/gates; int8 VALU recurrence.
// r24 lstm: UNIT-PER-THREAD. 256 thr/block (1 wave/EU, waves_per_eu(1,1) -> 512-VGPR budget);
//   thread u holds all 4 gate rows of unit u over full k in 64 uint4 (256 VGPR). No pbuf, no k-split,
//   thread-local elementwise, double-buffered hq8 + ONE barrier/step. int32 acc exact over full k.
//   Convs/gates frozen at r23 (64x64 conv wave tile).
// ws:    A f16 @0 (32,768,000) | G f16 [2][100][32][1024] @32,768,000 (13,107,200)
//        | state @45,875,200 (131,072) | W8 @46,006,272 (524,288) | scl f32[2048] @46,530,560 (8,192)
//        | Wg f16 [2][1024][512] @47,054,848 (2,097,152) -> 49,152,000 B
// d_out: Bd (conv1 out) @0 | Wp0 @36,000,000 | Wp1 @36,409,600 | Wp2 @41,652,480 | Xt0 @46,895,360

#define T_LEN 1000
#define NBATCH 32
#define CCH 512
#define HDIM 256
#define GDIM 1024
#define TC 100

typedef _Float16 h16;
typedef _Float16 h16x2 __attribute__((ext_vector_type(2)));
typedef _Float16 f16x8 __attribute__((ext_vector_type(8)));
typedef float    f32x4 __attribute__((ext_vector_type(4)));

__device__ __forceinline__ float fixup(float v, float alt){
    union { float f; unsigned u; } c; c.f = v;
    return ((c.u & 0x7f800000u) == 0x7f800000u) ? alt : v;
}
__device__ __forceinline__ float clamp_s(float v, float lo, float hi){
    return fminf(fmaxf(v, lo), hi);
}
__device__ __forceinline__ float sigm(float x){
    const float xc = clamp_s(x, -30.f, 30.f);
    return 1.0f / (1.0f + __expf(-xc));
}
__device__ __forceinline__ float tanh_safe(float x){
    const float ax = fminf(fabsf(x), 30.0f);
    const float t  = __expf(-2.0f * ax);
    const float r  = (1.0f - t) / (1.0f + t);
    return copysignf(r, x);
}
// v_dot4_i32_i8: 4 int8 MACs + i32 accumulate
__device__ __forceinline__ int dot4i8(int a, int b, int c){
#if defined(__has_builtin) && __has_builtin(__builtin_amdgcn_sdot4)
    return __builtin_amdgcn_sdot4(a, b, c, false);
#else
    int r = c;
    #pragma unroll
    for (int k = 0; k < 4; ++k) {
        const int av = (a << (24 - 8*k)) >> 24;
        const int bv = (b << (24 - 8*k)) >> 24;
        r += av * bv;
    }
    return r;
#endif
}

// ---------------- packs ----------------
__global__ __launch_bounds__(256)
void pack_convw_kernel(const float* __restrict__ cw, h16* __restrict__ Wp, int cin)
{
    const int n = blockIdx.x*256 + threadIdx.x;
    if (n >= 5*512*cin) return;
    const int k   = n / (512*cin);
    const int rem = n - k*512*cin;
    const int co  = rem / cin;
    const int ci  = rem - co*cin;
    Wp[n] = (h16)cw[((size_t)co*cin + ci)*5 + k];
}

__global__ __launch_bounds__(256)
void pack_wih_kernel(const float* __restrict__ wf, const float* __restrict__ wb, h16* __restrict__ Wg)
{
    const int n = blockIdx.x*256 + threadIdx.x;
    const float* src = (n < 1024*512) ? wf : wb;
    Wg[n] = (h16)src[n & (1024*512 - 1)];
}

// per-row |max| -> dot-scale scl[dir*1024+row] = max/(127*127)
__global__ __launch_bounds__(256)
void whh_scale_kernel(const float* __restrict__ whh_f, const float* __restrict__ whh_b,
                      float* __restrict__ scl)
{
    const int n = blockIdx.x*256 + threadIdx.x;   // 2048
    if (n >= 2048) return;
    const float* whh = (n >= 1024) ? whh_b : whh_f;
    const int row = n & 1023;
    float m = 0.f;
    for (int k = 0; k < HDIM; ++k) m = fmaxf(m, fabsf(whh[(size_t)row*HDIM + k]));
    scl[n] = fmaxf(m, 1e-8f) / 16129.0f;
}

// whh f32 -> int8 unit-per-thread pack (r24).
// uint4 [dir][slot 0..63][u 0..255]: slot = rg*16 + jj; row = rg*256 + u (rg: gate i/f/g/o);
// uint4 covers k = 16*jj .. 16*jj+15.  u32 n = dir*65536 + slot*1024 + u*4 + e; k0 = 16*jj + 4*e.
__global__ __launch_bounds__(256)
void whh_prep_kernel(const float* __restrict__ whh_f, const float* __restrict__ whh_b,
                     const float* __restrict__ scl, unsigned* __restrict__ W8)
{
    const int n = blockIdx.x * 256 + threadIdx.x;   // 131072 u32
    if (n >= 2*64*1024) return;
    const int dir  = n >> 16;
    const int rem  = n & 65535;
    const int slot = rem >> 10;
    const int idx  = rem & 1023;
    const int u    = idx >> 2;
    const int e    = idx & 3;
    const float* whh = dir ? whh_b : whh_f;
    const int rg  = slot >> 4;
    const int jj  = slot & 15;
    const int row = rg*256 + u;
    const float inv = 1.0f / (scl[dir*1024 + row] * 127.0f);   // = 127/max
    const int k0 = 16*jj + 4*e;
    unsigned uv = 0;
    #pragma unroll
    for (int j = 0; j < 4; ++j) {
        const float w = whh[(size_t)row*HDIM + k0 + j];
        int qv = (int)rintf(w * inv);
        qv = qv > 127 ? 127 : (qv < -127 ? -127 : qv);
        uv |= ((unsigned)(qv & 0xFF)) << (8*j);
    }
    W8[n] = uv;
}

__global__ __launch_bounds__(256)
void x0_transpose_kernel(const float* __restrict__ x, h16* __restrict__ Xt0)
{
    const int b = blockIdx.y;
    const int t = blockIdx.x*256 + threadIdx.x;
    if (t >= T_LEN) return;
    h16 v[80];
    #pragma unroll
    for (int c = 0; c < 80; ++c) v[c] = (h16)x[((size_t)b*80 + c)*T_LEN + t];
    #pragma unroll
    for (int g = 0; g < 10; ++g)
        *(f16x8*)(Xt0 + ((size_t)b*T_LEN + t)*80 + g*8) = *(const f16x8*)(v + g*8);
}

// ---------------- conv (implicit GEMM, MFMA 16x16x32 f16), 64x64 wave tile (r23, frozen) --------------
template<int CIN>
__global__ __attribute__((amdgpu_flat_work_group_size(512,512), amdgpu_waves_per_eu(2,4)))
void conv_mfma_kernel(const h16* __restrict__ Xt, const h16* __restrict__ Wp,
                      h16* __restrict__ outp,
                      const float* __restrict__ cb, const float* __restrict__ bg,
                      const float* __restrict__ bb, const float* __restrict__ bm,
                      const float* __restrict__ bv)
{
    const int t0   = blockIdx.x * 256;
    const int co0  = blockIdx.y * 128;
    const int b    = blockIdx.z;
    const int tid  = threadIdx.x;
    const int lane = tid & 63;
    const int w    = tid >> 6;
    const int wm   = w >> 1;
    const int wn   = w & 1;
    const int lr   = lane & 15;
    const int lg   = lane >> 4;

    __shared__ __align__(16) h16 Xs[260*40];
    __shared__ __align__(16) h16 Ws[5*128*40];

    f32x4 acc[4][4];
    #pragma unroll
    for (int m = 0; m < 4; ++m)
        #pragma unroll
        for (int n = 0; n < 4; ++n)
            #pragma unroll
            for (int r = 0; r < 4; ++r) acc[m][n][r] = 0.f;

    constexpr int KSTEPS = (CIN + 31) >> 5;
    for (int cs = 0; cs < KSTEPS; ++cs) {
        const int c0 = cs << 5;
        for (int id = tid; id < 260*4; id += 512) {
            const int row = id >> 2, g = id & 3;
            const int t = t0 + row - 2;
            f16x8 v;
            #pragma unroll
            for (int j = 0; j < 8; ++j) v[j] = (h16)0.f;
            if (t >= 0 && t < T_LEN) {
                const int c = c0 + g*8;
                if (c + 8 <= CIN) {
                    v = *(const f16x8*)(Xt + ((size_t)b*T_LEN + t)*CIN + c);
                } else if (c < CIN) {
                    #pragma unroll
                    for (int j = 0; j < 8; ++j) if (c + j < CIN) v[j] = Xt[((size_t)b*T_LEN + t)*CIN + c + j];
                }
            }
            *(f16x8*)(Xs + row*40 + g*8) = v;
        }
        for (int id = tid; id < 5*128*4; id += 512) {
            const int k  = id >> 9;
            const int co = (id >> 2) & 127;
            const int g  = id & 3;
            const int c  = c0 + g*8;
            f16x8 v;
            #pragma unroll
            for (int j = 0; j < 8; ++j) v[j] = (h16)0.f;
            if (c + 8 <= CIN) {
                v = *(const f16x8*)(Wp + ((size_t)k*512 + co0 + co)*CIN + c);
            } else if (c < CIN) {
                #pragma unroll
                for (int j = 0; j < 8; ++j) if (c + j < CIN) v[j] = Wp[((size_t)k*512 + co0 + co)*CIN + c + j];
            }
            *(f16x8*)(Ws + (k*128 + co)*40 + g*8) = v;
        }
        __syncthreads();

        #pragma unroll
        for (int k = 0; k < 5; ++k) {
            f16x8 bfr[4];
            #pragma unroll
            for (int nf = 0; nf < 4; ++nf)
                bfr[nf] = *(const f16x8*)(Ws + (k*128 + wn*64 + nf*16 + lr)*40 + lg*8);
            #pragma unroll
            for (int m = 0; m < 4; ++m) {
                const f16x8 a = *(const f16x8*)(Xs + (wm*64 + m*16 + lr + k)*40 + lg*8);
                #pragma unroll
                for (int nf = 0; nf < 4; ++nf)
                    acc[m][nf] = __builtin_amdgcn_mfma_f32_16x16x32_f16(a, bfr[nf], acc[m][nf], 0, 0, 0);
            }
        }
        __syncthreads();
    }

    #pragma unroll
    for (int nf = 0; nf < 4; ++nf) {
        const int co = co0 + wn*64 + nf*16 + lr;
        const float s  = bg[co] * rsqrtf(fmaxf(bv[co] + 1e-5f, 1e-8f));
        const float sh = (cb[co] - bm[co]) * s + bb[co];
        #pragma unroll
        for (int m = 0; m < 4; ++m) {
            #pragma unroll
            for (int r = 0; r < 4; ++r) {
                const int t = t0 + wm*64 + m*16 + lg*4 + r;
                if (t < T_LEN) {
                    const float y = fixup(clamp_s(fmaxf(acc[m][nf][r]*s + sh, 0.f), 0.f, 60000.f), 0.f);
                    outp[((size_t)b*T_LEN + t)*CCH + co] = (h16)y;
                }
            }
        }
    }
}

// ---------------- gates GEMM (MFMA), one time-chunk, both dirs (frozen) ----------------
__global__ __attribute__((amdgpu_flat_work_group_size(256,256), amdgpu_waves_per_eu(4,4)))
void gates_mfma_kernel(const h16* __restrict__ Xt,
                       const h16* __restrict__ Wg,
                       const float* __restrict__ bih_f, const float* __restrict__ bhh_f,
                       const float* __restrict__ bih_b, const float* __restrict__ bhh_b,
                       h16* __restrict__ G, int t0f, int t0b)
{
    const int tt   = blockIdx.x;
    const int r0   = blockIdx.y * 128;
    const int b    = blockIdx.z & 31;
    const int dir  = blockIdx.z >> 5;
    const int t0c  = dir ? t0b : t0f;
    const int tid  = threadIdx.x;
    const int lane = tid & 63;
    const int w    = tid >> 6;
    const int lr   = lane & 15;
    const int lg   = lane >> 4;
    const float* bi = dir ? bih_b : bih_f;
    const float* bh = dir ? bhh_b : bhh_f;
    const h16* Wd = Wg + (size_t)dir*1024*512;

    __shared__ __align__(16) h16 Xs[64*40];
    __shared__ __align__(16) h16 Ws[128*40];

    f32x4 acc[4][2];
    #pragma unroll
    for (int m = 0; m < 4; ++m)
        #pragma unroll
        for (int n = 0; n < 2; ++n)
            #pragma unroll
            for (int r = 0; r < 4; ++r) acc[m][n][r] = 0.f;

    for (int cs = 0; cs < 16; ++cs) {
        const int c0 = cs << 5;
        for (int id = tid; id < 64*4; id += 256) {
            const int row = id >> 2, g = id & 3;
            int t = t0c + tt*64 + row; if (t >= T_LEN) t = T_LEN - 1;
            *(f16x8*)(Xs + row*40 + g*8) = *(const f16x8*)(Xt + ((size_t)b*T_LEN + t)*CCH + c0 + g*8);
        }
        for (int id = tid; id < 128*4; id += 256) {
            const int row = id >> 2, g = id & 3;
            *(f16x8*)(Ws + row*40 + g*8) = *(const f16x8*)(Wd + (size_t)(r0 + row)*CCH + c0 + g*8);
        }
        __syncthreads();

        const f16x8 b0 = *(const f16x8*)(Ws + (w*32 +      lr)*40 + lg*8);
        const f16x8 b1 = *(const f16x8*)(Ws + (w*32 + 16 + lr)*40 + lg*8);
        #pragma unroll
        for (int m = 0; m < 4; ++m) {
            const f16x8 a = *(const f16x8*)(Xs + (m*16 + lr)*40 + lg*8);
            acc[m][0] = __builtin_amdgcn_mfma_f32_16x16x32_f16(a, b0, acc[m][0], 0, 0, 0);
            acc[m][1] = __builtin_amdgcn_mfma_f32_16x16x32_f16(a, b1, acc[m][1], 0, 0, 0);
        }
        __syncthreads();
    }

    #pragma unroll
    for (int nf = 0; nf < 2; ++nf) {
        const int row = r0 + w*32 + nf*16 + lr;
        const float bias = bi[row] + bh[row];
        #pragma unroll
        for (int m = 0; m < 4; ++m) {
            #pragma unroll
            for (int r = 0; r < 4; ++r) {
                const int tl = tt*64 + m*16 + lg*4 + r;
                if (tl < TC)
                    G[(((size_t)dir*TC + tl)*NBATCH + b)*GDIM + row]
                        = (h16)fixup(clamp_s(acc[m][nf][r] + bias, -60000.f, 60000.f), 0.f);
            }
        }
    }
}

// ---------------- persistent biLSTM recurrence: unit-per-thread, int8, 1 barrier/step ----------------
// 64 blocks = (dir,b), 256 threads. Thread u owns unit u: rows u, 256+u, 512+u, 768+u over FULL k
// in 64 uint4 regs (~256 VGPR; 1 wave/EU via waves_per_eu(1,1) -> 512-VGPR budget).
// h int8 double-buffered in LDS; per step: 1 ds_read_b32 + 64 readlane + 256 dot4 + local elementwise.
__global__ __attribute__((amdgpu_flat_work_group_size(256, 256), amdgpu_waves_per_eu(1, 1)))
void lstm_chunk_kernel(const h16* __restrict__ G,
                       const unsigned* __restrict__ W8,
                       const float* __restrict__ scl,
                       float* __restrict__ state,
                       float* __restrict__ out,
                       int t0f, int t0b, int first)
{
    const int u    = threadIdx.x;        // unit 0..255
    const int lane = u & 63;
    const int dir  = blockIdx.x >> 5;
    const int b    = blockIdx.x & 31;
    const int t0   = dir ? t0b : t0f;
    float* st = state + ((size_t)(dir*NBATCH + b))*2*HDIM;
    const uint4* Wv = (const uint4*)W8 + (size_t)dir*16384;   // [slot 0..63][u 0..255]

    __shared__ __align__(4) unsigned char hq8[2][256];        // double-buffered h int8

    // full weight residency: 64 uint4 (slot-major, coalesced over u)
    uint4 wr[64];
    #pragma unroll
    for (int s = 0; s < 64; ++s) wr[s] = Wv[s*256 + u];

    const float s0 = scl[dir*1024 +       u];
    const float s1 = scl[dir*1024 + 256 + u];
    const float s2 = scl[dir*1024 + 512 + u];
    const float s3 = scl[dir*1024 + 768 + u];

    float hst = 0.0f, cst = 0.0f;
    if (!first) { hst = st[u]; cst = st[HDIM + u]; }
    {
        const int qh = (int)rintf(clamp_s(hst, -1.f, 1.f) * 127.f);
        hq8[0][u] = (unsigned char)(qh & 0xFF);
    }
    __syncthreads();

    for (int i = 0; i < TC; ++i) {
        const int sl = dir ? (TC - 1 - i) : i;
        const int t  = t0 + sl;
        const h16* gp = G + (((size_t)dir*TC + sl)*NBATCH + b)*GDIM;

        // G loads issued early (hidden under dots)
        const float g0 = (float)gp[u];
        const float g1 = (float)gp[256 + u];
        const float g2 = (float)gp[512 + u];
        const float g3 = (float)gp[768 + u];

        // h k-chunk broadcast: lane l holds u32 l of this buffer (units 4l..4l+3)
        const unsigned wv = ((const unsigned*)hq8[i & 1])[lane];

        int a0 = 0, a1 = 0, a2 = 0, a3 = 0;
        #pragma unroll
        for (int jj = 0; jj < 16; ++jj) {
            const int h0 = __builtin_amdgcn_readlane((int)wv, 4*jj + 0);
            const int h1 = __builtin_amdgcn_readlane((int)wv, 4*jj + 1);
            const int h2 = __builtin_amdgcn_readlane((int)wv, 4*jj + 2);
            const int h3 = __builtin_amdgcn_readlane((int)wv, 4*jj + 3);
            const uint4 w0 = wr[      jj];   // gate i, k 16jj..16jj+15
            const uint4 w1 = wr[16 + jj];    // gate f
            const uint4 w2 = wr[32 + jj];    // gate g
            const uint4 w3 = wr[48 + jj];    // gate o
            a0 = dot4i8(h0, (int)w0.x, a0); a0 = dot4i8(h1, (int)w0.y, a0);
            a0 = dot4i8(h2, (int)w0.z, a0); a0 = dot4i8(h3, (int)w0.w, a0);
            a1 = dot4i8(h0, (int)w1.x, a1); a1 = dot4i8(h1, (int)w1.y, a1);
            a1 = dot4i8(h2, (int)w1.z, a1); a1 = dot4i8(h3, (int)w1.w, a1);
            a2 = dot4i8(h0, (int)w2.x, a2); a2 = dot4i8(h1, (int)w2.y, a2);
            a2 = dot4i8(h2, (int)w2.z, a2); a2 = dot4i8(h3, (int)w2.w, a2);
            a3 = dot4i8(h0, (int)w3.x, a3); a3 = dot4i8(h1, (int)w3.y, a3);
            a3 = dot4i8(h2, (int)w3.z, a3); a3 = dot4i8(h3, (int)w3.w, a3);
        }

        // thread-local elementwise (no exchange needed)
        const float gi = g0 + (float)a0 * s0;
        const float gf = g1 + (float)a1 * s1;
        const float gg = g2 + (float)a2 * s2;
        const float go = g3 + (float)a3 * s3;
        const float c2 = sigm(gf)*cst + sigm(gi)*tanh_safe(gg);
        const float h2v = sigm(go)*tanh_safe(c2);
        hst = 0.1f*hst + 0.9f*h2v;                  // zoneout (output is post-zoneout h)
        cst = 0.1f*cst + 0.9f*c2;
        out[((size_t)b*T_LEN + t)*(2*HDIM) + dir*HDIM + u] = fixup(hst, 50.0f);
        const int qh = (int)rintf(clamp_s(hst, -1.f, 1.f) * 127.f);
        hq8[(i + 1) & 1][u] = (unsigned char)(qh & 0xFF);   // write NEXT buffer (WAR-safe)
        __syncthreads();                            // the ONLY barrier per step
    }

    st[u] = hst; st[HDIM + u] = cst;
}

extern "C" void kernel_launch(void* const* d_in, const int* in_sizes, int n_in,
                              void* d_out, int out_size, void* d_ws, size_t ws_size,
                              hipStream_t stream)
{
    (void)in_sizes; (void)n_in; (void)out_size;
    if (ws_size < 49152000) return;

    const float* x     = (const float*)d_in[0];
    const float* cw0   = (const float*)d_in[1];
    const float* cb0   = (const float*)d_in[2];
    const float* bg0   = (const float*)d_in[3];
    const float* bb0   = (const float*)d_in[4];
    const float* bm0   = (const float*)d_in[5];
    const float* bv0   = (const float*)d_in[6];
    const float* cw1   = (const float*)d_in[7];
    const float* cb1   = (const float*)d_in[8];
    const float* bg1   = (const float*)d_in[9];
    const float* bb1   = (const float*)d_in[10];
    const float* bm1   = (const float*)d_in[11];
    const float* bv1   = (const float*)d_in[12];
    const float* cw2   = (const float*)d_in[13];
    const float* cb2   = (const float*)d_in[14];
    const float* bg2   = (const float*)d_in[15];
    const float* bb2   = (const float*)d_in[16];
    const float* bm2   = (const float*)d_in[17];
    const float* bv2   = (const float*)d_in[18];
    const float* wih_f = (const float*)d_in[19];
    const float* whh_f = (const float*)d_in[20];
    const float* bih_f = (const float*)d_in[21];
    const float* bhh_f = (const float*)d_in[22];
    const float* wih_b = (const float*)d_in[23];
    const float* whh_b = (const float*)d_in[24];
    const float* bih_b = (const float*)d_in[25];
    const float* bhh_b = (const float*)d_in[26];

    char* ws = (char*)d_ws;
    char* od = (char*)d_out;
    h16*      A   = (h16*)(ws);
    h16*      G   = (h16*)(ws + 32768000);
    float*    st  = (float*)(ws + 45875200);
    unsigned* W8  = (unsigned*)(ws + 46006272);
    float*    scl = (float*)(ws + 46530560);
    h16*      Wg  = (h16*)(ws + 47054848);
    h16*      Bd  = (h16*)(od);
    h16*      Wp0 = (h16*)(od + 36000000);
    h16*      Wp1 = (h16*)(od + 36409600);
    h16*      Wp2 = (h16*)(od + 41652480);
    h16*      Xt0 = (h16*)(od + 46895360);
    float*    out = (float*)d_out;

    // packs
    pack_convw_kernel<<<dim3((5*512*80  + 255)/256), 256, 0, stream>>>(cw0, Wp0, 80);
    pack_convw_kernel<<<dim3((5*512*512 + 255)/256), 256, 0, stream>>>(cw1, Wp1, 512);
    pack_convw_kernel<<<dim3((5*512*512 + 255)/256), 256, 0, stream>>>(cw2, Wp2, 512);
    pack_wih_kernel<<<dim3(2*1024*512/256), 256, 0, stream>>>(wih_f, wih_b, Wg);
    whh_scale_kernel<<<dim3(8), 256, 0, stream>>>(whh_f, whh_b, scl);
    whh_prep_kernel<<<dim3(512), 256, 0, stream>>>(whh_f, whh_b, scl, W8);
    x0_transpose_kernel<<<dim3(4, 32), 256, 0, stream>>>(x, Xt0);

    // convs (implicit-GEMM MFMA, 64x64 wave tile)
    const dim3 cgrid(4, 4, 32);
    conv_mfma_kernel<80> <<<cgrid, 512, 0, stream>>>(Xt0, Wp0, A,  cb0, bg0, bb0, bm0, bv0);
    conv_mfma_kernel<512><<<cgrid, 512, 0, stream>>>(A,   Wp1, Bd, cb1, bg1, bb1, bm1, bv1);
    conv_mfma_kernel<512><<<cgrid, 512, 0, stream>>>(Bd,  Wp2, A,  cb2, bg2, bb2, bm2, bv2);

    for (int c = 0; c < T_LEN / TC; ++c) {
        const int t0f = c * TC;
        const int t0b = (T_LEN - TC) - c * TC;
        gates_mfma_kernel<<<dim3(2, 8, 64), 256, 0, stream>>>(A, Wg, bih_f, bhh_f, bih_b, bhh_b, G, t0f, t0b);
        lstm_chunk_kernel<<<dim3(64), 256, 0, stream>>>(G, W8, scl, st, out, t0f, t0b, c == 0);
    }
}